// Round 5
// baseline (796.674 us; speedup 1.0000x reference)
//
#include <hip/hip_runtime.h>
#include <math.h>

#define N_NODES 50000
#define N_EDGES 400000
#define IN_F 128
#define HC 176
#define NGRAPH 64
#define NBLK_ATTN 25000   // N_NODES/2 — R15: 2 nodes/block, 2 waves per node
#define NCHUNK 16         // part_reduce chunks per graph

typedef _Float16 half8 __attribute__((ext_vector_type(8)));
typedef _Float16 half4 __attribute__((ext_vector_type(4)));
typedef float floatx4 __attribute__((ext_vector_type(4)));

__device__ inline float4 h4f(const _Float16* p) {
  half4 h = *(const half4*)p;
  return make_float4((float)h[0], (float)h[1], (float)h[2], (float)h[3]);
}

// =====================================================================
// Packed split-fp16 weights in MFMA B-fragment order.
// =====================================================================
#define PREH 45056   // 4*11*2*512 halves
#define MATH 67584   // 6*11*2*512 halves
#define TOT_PAIRS 495616  // 22528 + 14*33792
#define KCBYTES 22528     // bytes per kc chunk (11*2*512*2)
#define GX8 49            // row-tile groups of 8 (49*8=392 >= 391 tiles)

__global__ void prep_kernel(const float* __restrict__ Wpre,
                            const float* __restrict__ cWl, const float* __restrict__ cWr,
                            const float* __restrict__ cWres,
                            const float* __restrict__ c5Wl, const float* __restrict__ c5Wr,
                            _Float16* __restrict__ wp) {
  int gid = blockIdx.x * 256 + threadIdx.x;
  if (gid >= TOT_PAIRS) return;
  int mat, idx;
  if (gid < 22528) { mat = 0; idx = gid; }
  else { int g = gid - 22528; mat = 1 + g / 33792; idx = g % 33792; }
  int kc = idx / 5632;
  int rem = idx - kc * 5632;
  int ct = rem / 512;
  int li = rem - ct * 512;
  int lane = li >> 3, j = li & 7;
  int k = kc * 32 + ((lane >> 4) << 3) + j;
  int col = ct * 16 + (lane & 15);
  const float* src; int Ksrc; size_t base;
  if (mat == 0) { src = Wpre; Ksrc = 128; base = 0; }
  else if (mat <= 12) {
    int lm = mat - 1; int layer = lm / 3; int sub = lm - layer * 3;
    const float* s = (sub == 0) ? cWl : (sub == 1) ? cWr : cWres;
    src = s + (size_t)layer * HC * HC; Ksrc = HC;
    base = PREH + (size_t)lm * MATH;
  } else {
    src = (mat == 13) ? c5Wl : c5Wr; Ksrc = HC;
    base = PREH + (size_t)12 * MATH + (size_t)(mat - 13) * MATH;
  }
  float v = (k < Ksrc) ? src[(size_t)k * HC + col] : 0.0f;
  _Float16 h = (_Float16)v;
  _Float16 l = (_Float16)(v - (float)h);
  size_t o = base + (size_t)(kc * 11 + ct) * 1024 + li;
  wp[o] = h;
  wp[o + 512] = l;
}

// =====================================================================
// Split-fp16 MFMA GEMM with block-level LDS staging of B + XCD swizzle.
// AHALF: A stored fp16 (trunk). halfMask: bit per mat -> fp16 output.
// grid.x = GX8 * nmat * 8.
// =====================================================================
template <int MINW, bool DOSTATS, bool AHALF>
__global__ __launch_bounds__(256, MINW) void gemm_mfma_t(
    const float* __restrict__ A, int M, int K, int nkc, int nmat,
    const _Float16* __restrict__ Wp, int matStride,
    const float* __restrict__ scsh, const int* __restrict__ batch,
    const float* __restrict__ bias0, const float* __restrict__ bias1,
    const float* __restrict__ bias2,
    float* __restrict__ out0, float* __restrict__ out1, float* __restrict__ out2,
    float* __restrict__ parts, float* __restrict__ partq, float* __restrict__ stats,
    int halfMask) {
  __shared__ __align__(16) char smem[2 * KCBYTES];
  const int b = blockIdx.x;
  const int grp = b >> 3, sub = b & 7;
  const int mat = grp % nmat;
  const int tile = ((grp / nmat) << 3) | sub;
  if (tile * 128 >= M) return;
  const _Float16* W = Wp + (size_t)mat * matStride;
  float* outp = (mat == 0) ? out0 : (mat == 1) ? out1 : out2;
  const float* bias = (mat == 0) ? bias0 : (mat == 1) ? bias1 : bias2;
  const bool hOut = (halfMask >> mat) & 1;
  const int tid = threadIdx.x;
  const int lane = tid & 63;
  const int wv = tid >> 6;
  const int m16 = lane & 15, quad = lane >> 4;
  const int kb = quad << 3;
  const int rowBase = tile * 128 + wv * 32;
  const int rA0 = min(rowBase + m16, M - 1);
  const int rA1 = min(rowBase + 16 + m16, M - 1);
  const float* ap0 = A + (size_t)rA0 * K + kb;
  const float* ap1 = A + (size_t)rA1 * K + kb;
  const _Float16* hp0 = (const _Float16*)A + (size_t)rA0 * K + kb;
  const _Float16* hp1 = (const _Float16*)A + (size_t)rA1 * K + kb;
  const float* sc0 = nullptr; const float* sh0 = nullptr;
  const float* sc1 = nullptr; const float* sh1 = nullptr;
  if (scsh) {
    int g0 = batch[rA0], g1 = batch[rA1];
    sc0 = scsh + (size_t)g0 * HC + kb;
    sh0 = scsh + (size_t)(NGRAPH + g0) * HC + kb;
    sc1 = scsh + (size_t)g1 * HC + kb;
    sh1 = scsh + (size_t)(NGRAPH + g1) * HC + kb;
  }

  auto stage = [&](int kc, int buf) {
    const char* src = (const char*)W + (size_t)kc * KCBYTES;
    char* dst = smem + buf * KCBYTES;
#pragma unroll
    for (int i = 0; i < 6; i++) {
      int idx = wv * 6 + i;
      if (idx < 22) {
        __builtin_amdgcn_global_load_lds(
            (const __attribute__((address_space(1))) unsigned int*)(src + idx * 1024 + lane * 16),
            (__attribute__((address_space(3))) unsigned int*)(dst + idx * 1024),
            16, 0, 0);
      }
    }
  };

  floatx4 acc0[11], acc1[11];
#pragma unroll
  for (int ct = 0; ct < 11; ct++)
#pragma unroll
    for (int r = 0; r < 4; r++) { acc0[ct][r] = 0.0f; acc1[ct][r] = 0.0f; }

  stage(0, 0);

  for (int kc = 0; kc < nkc; kc++) {
    const int buf = kc & 1;
    __syncthreads();
    if (kc + 1 < nkc) stage(kc + 1, 1 - buf);

    const int koff = kc << 5;
    float va0[8], va1[8];
    if (koff + kb + 8 <= K) {
      if (AHALF) {
        half8 u = *(const half8*)(hp0 + koff);
        half8 w = *(const half8*)(hp1 + koff);
#pragma unroll
        for (int j = 0; j < 8; j++) { va0[j] = (float)u[j]; va1[j] = (float)w[j]; }
      } else {
        float4 u0 = *(const float4*)(ap0 + koff);
        float4 u1 = *(const float4*)(ap0 + koff + 4);
        float4 w0 = *(const float4*)(ap1 + koff);
        float4 w1 = *(const float4*)(ap1 + koff + 4);
        va0[0] = u0.x; va0[1] = u0.y; va0[2] = u0.z; va0[3] = u0.w;
        va0[4] = u1.x; va0[5] = u1.y; va0[6] = u1.z; va0[7] = u1.w;
        va1[0] = w0.x; va1[1] = w0.y; va1[2] = w0.z; va1[3] = w0.w;
        va1[4] = w1.x; va1[5] = w1.y; va1[6] = w1.z; va1[7] = w1.w;
      }
      if (scsh) {
        float s0[8], h0[8], s1[8], h1[8];
        float4 t;
        t = *(const float4*)(sc0 + koff);     s0[0]=t.x; s0[1]=t.y; s0[2]=t.z; s0[3]=t.w;
        t = *(const float4*)(sc0 + koff + 4); s0[4]=t.x; s0[5]=t.y; s0[6]=t.z; s0[7]=t.w;
        t = *(const float4*)(sh0 + koff);     h0[0]=t.x; h0[1]=t.y; h0[2]=t.z; h0[3]=t.w;
        t = *(const float4*)(sh0 + koff + 4); h0[4]=t.x; h0[5]=t.y; h0[6]=t.z; h0[7]=t.w;
        t = *(const float4*)(sc1 + koff);     s1[0]=t.x; s1[1]=t.y; s1[2]=t.z; s1[3]=t.w;
        t = *(const float4*)(sc1 + koff + 4); s1[4]=t.x; s1[5]=t.y; s1[6]=t.z; s1[7]=t.w;
        t = *(const float4*)(sh1 + koff);     h1[0]=t.x; h1[1]=t.y; h1[2]=t.z; h1[3]=t.w;
        t = *(const float4*)(sh1 + koff + 4); h1[4]=t.x; h1[5]=t.y; h1[6]=t.z; h1[7]=t.w;
#pragma unroll
        for (int j = 0; j < 8; j++) {
          va0[j] = fmaxf(fmaf(va0[j], s0[j], h0[j]), 0.0f);
          va1[j] = fmaxf(fmaf(va1[j], s1[j], h1[j]), 0.0f);
        }
      }
    } else {
#pragma unroll
      for (int j = 0; j < 8; j++) { va0[j] = 0.0f; va1[j] = 0.0f; }
    }
    half8 ah0, al0, ah1, al1;
#pragma unroll
    for (int j = 0; j < 8; j++) {
      _Float16 h = (_Float16)va0[j];
      ah0[j] = h; al0[j] = (_Float16)(va0[j] - (float)h);
      _Float16 g = (_Float16)va1[j];
      ah1[j] = g; al1[j] = (_Float16)(va1[j] - (float)g);
    }
    const char* bbase = smem + buf * KCBYTES + lane * 16;
#pragma unroll
    for (int ct = 0; ct < 11; ct++) {
      half8 bh = *(const half8*)(bbase + ct * 2048);
      half8 bl = *(const half8*)(bbase + ct * 2048 + 1024);
      acc0[ct] = __builtin_amdgcn_mfma_f32_16x16x32_f16(ah0, bh, acc0[ct], 0, 0, 0);
      acc1[ct] = __builtin_amdgcn_mfma_f32_16x16x32_f16(ah1, bh, acc1[ct], 0, 0, 0);
      acc0[ct] = __builtin_amdgcn_mfma_f32_16x16x32_f16(al0, bh, acc0[ct], 0, 0, 0);
      acc1[ct] = __builtin_amdgcn_mfma_f32_16x16x32_f16(al1, bh, acc1[ct], 0, 0, 0);
      acc0[ct] = __builtin_amdgcn_mfma_f32_16x16x32_f16(ah0, bl, acc0[ct], 0, 0, 0);
      acc1[ct] = __builtin_amdgcn_mfma_f32_16x16x32_f16(ah1, bl, acc1[ct], 0, 0, 0);
    }
  }

  float bv[11];
#pragma unroll
  for (int ct = 0; ct < 11; ct++) bv[ct] = bias ? bias[ct * 16 + m16] : 0.0f;
#pragma unroll
  for (int r = 0; r < 4; r++) {
    int row0 = rowBase + (quad << 2) + r;
    if (row0 < M) {
      if (hOut) {
        _Float16* op = (_Float16*)outp + (size_t)row0 * HC + m16;
#pragma unroll
        for (int ct = 0; ct < 11; ct++) op[ct * 16] = (_Float16)(acc0[ct][r] + bv[ct]);
      } else {
        float* op = outp + (size_t)row0 * HC + m16;
#pragma unroll
        for (int ct = 0; ct < 11; ct++) op[ct * 16] = acc0[ct][r] + bv[ct];
      }
    }
    int row1 = row0 + 16;
    if (row1 < M) {
      if (hOut) {
        _Float16* op = (_Float16*)outp + (size_t)row1 * HC + m16;
#pragma unroll
        for (int ct = 0; ct < 11; ct++) op[ct * 16] = (_Float16)(acc1[ct][r] + bv[ct]);
      } else {
        float* op = outp + (size_t)row1 * HC + m16;
#pragma unroll
        for (int ct = 0; ct < 11; ct++) op[ct * 16] = acc1[ct][r] + bv[ct];
      }
    }
  }

  if (DOSTATS) {
    // ---- fused GraphNorm per-tile partials (128 rows, <=2 graphs) ----
    int gTile = batch[tile * 128];  // tile*128 < M guaranteed
    int lastRow = min(tile * 128 + 127, M - 1);
    bool straddle = (batch[lastRow] != gTile);
    bool validR[8]; bool otherR[8];
#pragma unroll
    for (int r = 0; r < 4; r++) {
      int row0 = rowBase + (quad << 2) + r;
      validR[r] = (row0 < M);
      otherR[r] = validR[r] && (batch[min(row0, M - 1)] != gTile);
      int row1 = row0 + 16;
      validR[4 + r] = (row1 < M);
      otherR[4 + r] = validR[4 + r] && (batch[min(row1, M - 1)] != gTile);
    }
    __syncthreads();  // staging LDS no longer needed; reuse for reduction
    float* red = (float*)smem;  // [4][11][16][4]
#pragma unroll
    for (int ct = 0; ct < 11; ct++) {
      float sA = 0.f, qA = 0.f, sB = 0.f, qB = 0.f;
#pragma unroll
      for (int r = 0; r < 4; r++) {
        if (validR[r]) {
          float v = acc0[ct][r] + bv[ct];
          if (otherR[r]) { sB += v; qB = fmaf(v, v, qB); }
          else           { sA += v; qA = fmaf(v, v, qA); }
        }
        if (validR[4 + r]) {
          float v = acc1[ct][r] + bv[ct];
          if (otherR[4 + r]) { sB += v; qB = fmaf(v, v, qB); }
          else               { sA += v; qA = fmaf(v, v, qA); }
        }
      }
      sA += __shfl_xor(sA, 16); sA += __shfl_xor(sA, 32);
      qA += __shfl_xor(qA, 16); qA += __shfl_xor(qA, 32);
      sB += __shfl_xor(sB, 16); sB += __shfl_xor(sB, 32);
      qB += __shfl_xor(qB, 16); qB += __shfl_xor(qB, 32);
      if (quad == 0) {
        float* slot = red + (((wv * 11 + ct) * 16 + m16) << 2);
        slot[0] = sA; slot[1] = qA; slot[2] = sB; slot[3] = qB;
      }
    }
    __syncthreads();
    if (tid < HC) {
      int col = tid;
      float sA = 0.f, qA = 0.f, sB = 0.f, qB = 0.f;
#pragma unroll
      for (int w = 0; w < 4; w++) {
        float* slot = red + (((w * 11 + col / 16) * 16 + (col & 15)) << 2);
        sA += slot[0]; qA += slot[1]; sB += slot[2]; qB += slot[3];
      }
      parts[(size_t)tile * HC + col] = sA;
      partq[(size_t)tile * HC + col] = qA;
      if (straddle) {
        int g2 = batch[lastRow];
        atomicAdd(&stats[g2 * HC + col], sB);
        atomicAdd(&stats[(NGRAPH + g2) * HC + col], qB);
      }
    }
  }
}

// =====================================================================
// Reduce per-block partials into stats. rpb = rows-per-partial-block
// (2 for attention partials, 128 for pre-GEMM tile partials).
// =====================================================================
__global__ __launch_bounds__(256) void part_reduce_kernel(
    const float* __restrict__ parts, const float* __restrict__ partq,
    const int* __restrict__ gstart, float* __restrict__ stats, int rpb) {
  int idx = blockIdx.x * 256 + threadIdx.x;
  if (idx >= NGRAPH * NCHUNK * HC) return;
  int f = idx % HC;
  int gc = idx / HC;
  int g = gc / NCHUNK, c = gc % NCHUNK;
  int s0 = gstart[g], s1 = gstart[g + 1];
  int b0 = (s0 + rpb - 1) / rpb, b1 = (s1 + rpb - 1) / rpb;
  int len = b1 - b0;
  if (len <= 0) return;
  int per = (len + NCHUNK - 1) / NCHUNK;
  int cb0 = b0 + c * per;
  int cb1 = min(cb0 + per, b1);
  if (cb0 >= cb1) return;
  float s = 0.f, ss = 0.f;
  for (int b = cb0; b < cb1; b++) {
    s += parts[(size_t)b * HC + f];
    ss += partq[(size_t)b * HC + f];
  }
  atomicAdd(&stats[g * HC + f], s);
  atomicAdd(&stats[(NGRAPH + g) * HC + f], ss);
}

__global__ void gn_finalize_kernel(const float* __restrict__ stats, const int* __restrict__ cntInt,
                                   const float* __restrict__ gnw, const float* __restrict__ gnb,
                                   const float* __restrict__ gnms, int row,
                                   float* __restrict__ scsh) {
  int i = blockIdx.x * 256 + threadIdx.x;
  if (i >= NGRAPH * HC) return;
  int g = i / HC, f = i - g * HC;
  float c = fmaxf((float)cntInt[g], 1.0f);
  float m = stats[i] / c;
  float sq = stats[NGRAPH * HC + i] / c;
  float ms = gnms[row * HC + f];
  float var = sq - m * m * ms * (2.0f - ms);
  float w = gnw[row * HC + f], b = gnb[row * HC + f];
  float scale = w / sqrtf(var + 1e-5f);
  float shift = b - scale * ms * m;
  scsh[i] = scale;
  scsh[NGRAPH * HC + i] = shift;
}

// =====================================================================
// Per-graph counts + start offsets via binary search (batch sorted).
// =====================================================================
__global__ void cnt_bsearch_kernel(const int* __restrict__ batch, int* __restrict__ cntInt,
                                   int* __restrict__ gstart) {
  int g = threadIdx.x;
  if (g >= NGRAPH) return;
  auto lb = [&](int v) {
    int lo = 0, hi = N_NODES;
    while (lo < hi) {
      int mid = (lo + hi) >> 1;
      if (batch[mid] < v) lo = mid + 1; else hi = mid;
    }
    return lo;
  };
  int a = lb(g), b = lb(g + 1);
  cntInt[g] = b - a;
  gstart[g] = a;
  if (g == NGRAPH - 1) gstart[NGRAPH] = N_NODES;
}

// =====================================================================
// CSR build by destination
// =====================================================================
__global__ void deg_hist_kernel(const int* __restrict__ dstE, int* __restrict__ deg) {
  int e = blockIdx.x * 256 + threadIdx.x;
  if (e < N_EDGES) atomicAdd(&deg[dstE[e]], 1);
}

__global__ void scan1_kernel(const int* __restrict__ deg, int* __restrict__ bsum) {
  __shared__ int sd[256];
  int i = blockIdx.x * 256 + threadIdx.x;
  sd[threadIdx.x] = (i < N_NODES) ? deg[i] : 0;
  __syncthreads();
  for (int s = 128; s > 0; s >>= 1) {
    if (threadIdx.x < s) sd[threadIdx.x] += sd[threadIdx.x + s];
    __syncthreads();
  }
  if (threadIdx.x == 0) bsum[blockIdx.x] = sd[0];
}

__global__ void scan2_kernel(int* __restrict__ bsum, int nb) {
  __shared__ int sd[256];
  int t = threadIdx.x;
  int v0 = (t < nb) ? bsum[t] : 0;
  sd[t] = v0;
  __syncthreads();
  for (int s = 1; s < 256; s <<= 1) {
    int v = (t >= s) ? sd[t - s] : 0;
    __syncthreads();
    sd[t] += v;
    __syncthreads();
  }
  if (t < nb) bsum[t] = sd[t] - v0;  // exclusive
}

__global__ void scan3_kernel(const int* __restrict__ deg, const int* __restrict__ bsum,
                             int* __restrict__ rowptr) {
  __shared__ int sd[256];
  int i = blockIdx.x * 256 + threadIdx.x;
  int t = threadIdx.x;
  int d = (i < N_NODES) ? deg[i] : 0;
  sd[t] = d;
  __syncthreads();
  for (int s = 1; s < 256; s <<= 1) {
    int v = (t >= s) ? sd[t - s] : 0;
    __syncthreads();
    sd[t] += v;
    __syncthreads();
  }
  if (i < N_NODES) rowptr[i] = bsum[blockIdx.x] + sd[t] - d;
  if (i == 0) rowptr[N_NODES] = N_EDGES;
}

__global__ void scatter_kernel(const int* __restrict__ srcE, const int* __restrict__ dstE,
                               const int* __restrict__ rowptr, int* __restrict__ fill,
                               int* __restrict__ colA) {
  int e = blockIdx.x * 256 + threadIdx.x;
  if (e < N_EDGES) {
    int d = dstE[e];
    int pos = rowptr[d] + atomicAdd(&fill[d], 1);
    colA[pos] = srcE[e];
  }
}

// =====================================================================
// GATv2 attention + fused GraphNorm partials. fp16 xl/xr/trunk.
// R15: 2 WAVES PER NODE — each wave takes every-other edge (stride 2,
// 2-deep pipeline kept), halving the per-wave serial gather chain that
// R4's counters showed is the bottleneck (54us vs 21us byte-floor).
// Partials combined via LDS; wave 0 does the epilogue.
// =====================================================================
#define AEDGE(V, D, ACC)                                                      \
  do {                                                                        \
    float e0 = (V).x + xrv.x; e0 = fmaxf(e0, 0.2f * e0);                      \
    float e1 = (V).y + xrv.y; e1 = fmaxf(e1, 0.2f * e1);                      \
    float e2 = (V).z + xrv.z; e2 = fmaxf(e2, 0.2f * e2);                      \
    float e3 = (V).w + xrv.w; e3 = fmaxf(e3, 0.2f * e3);                      \
    float p = fmaf(e3, av.w, fmaf(e2, av.z, fmaf(e1, av.y, e0 * av.x)));      \
    p += __shfl_xor(p, 1);                                                    \
    p += __shfl_xor(p, 2);                                                    \
    float pp = __expf(p);                                                     \
    (D) += pp;                                                                \
    (ACC).x = fmaf(pp, (V).x, (ACC).x);                                       \
    (ACC).y = fmaf(pp, (V).y, (ACC).y);                                       \
    (ACC).z = fmaf(pp, (V).z, (ACC).z);                                       \
    (ACC).w = fmaf(pp, (V).w, (ACC).w);                                       \
  } while (0)

// stride-2, 2-deep pipeline over this wave's half of the edge list.
// wave wv handles edges start+wv, start+wv+2, ...; self-loop on wave 0.
#define ATTN_HALF_BODY(XLL)                                                   \
  int start = rowptr[node], end = rowptr[node + 1];                           \
  float dB = 0.0f;                                                            \
  float4 accB = make_float4(0.f, 0.f, 0.f, 0.f);                              \
  float4 p1, p2;                                                              \
  int j = start + wvp;                                                        \
  if (j < end)     p1 = h4f(xl + (size_t)colA[j] * HC + (XLL));               \
  if (j + 2 < end) p2 = h4f(xl + (size_t)colA[j + 2] * HC + (XLL));           \
  if (wvp == 0) {                                                             \
    float4 svv = h4f(xl + base);                                              \
    AEDGE(svv, d, acc);                                                       \
  }                                                                           \
  for (; j + 6 < end; j += 4) {                                               \
    float4 n1 = h4f(xl + (size_t)colA[j + 4] * HC + (XLL));                   \
    float4 n2 = h4f(xl + (size_t)colA[j + 6] * HC + (XLL));                   \
    AEDGE(p1, d, acc);                                                        \
    AEDGE(p2, dB, accB);                                                      \
    p1 = n1; p2 = n2;                                                         \
  }                                                                           \
  if (j < end)     AEDGE(p1, d, acc);                                         \
  if (j + 2 < end) AEDGE(p2, dB, accB);                                       \
  if (j + 4 < end) {                                                          \
    float4 n1 = h4f(xl + (size_t)colA[j + 4] * HC + (XLL));                   \
    AEDGE(n1, d, acc);                                                        \
  }                                                                           \
  d += dB;                                                                    \
  acc.x += accB.x; acc.y += accB.y; acc.z += accB.z; acc.w += accB.w;

__global__ __launch_bounds__(256) void attn_concat_kernel(
    const _Float16* __restrict__ xl, const _Float16* __restrict__ xr,
    const float* __restrict__ att, const int* __restrict__ rowptr,
    const int* __restrict__ colA, _Float16* __restrict__ out,
    const int* __restrict__ batch, float* __restrict__ stats,
    float* __restrict__ parts, float* __restrict__ partq) {
  __shared__ float sv[2 * HC];
  __shared__ float red[2][44][5];
  int t = threadIdx.x;
  int pair = t >> 7;          // which node of the block
  int wvp = (t >> 6) & 1;     // wave within the node's pair
  int lane = t & 63;
  int node = blockIdx.x * 2 + pair;   // grid = N/2 exactly
  float d = 0.0f;
  float4 acc = make_float4(0.f, 0.f, 0.f, 0.f);
  size_t base = (size_t)node * HC + lane * 4;  // valid for lane<44 only
  if (lane < 44) {
    const float4 av = *(const float4*)(att + lane * 4);
    const float4 xrv = h4f(xr + base);
    ATTN_HALF_BODY(lane * 4)
    if (wvp == 1) {
      red[pair][lane][0] = d;
      red[pair][lane][1] = acc.x; red[pair][lane][2] = acc.y;
      red[pair][lane][3] = acc.z; red[pair][lane][4] = acc.w;
    }
  }
  __syncthreads();
  if (wvp == 0 && lane < 44) {
    d += red[pair][lane][0];
    acc.x += red[pair][lane][1]; acc.y += red[pair][lane][2];
    acc.z += red[pair][lane][3]; acc.w += red[pair][lane][4];
    float rd = 1.0f / (d + 1e-16f);
    half4 rv = *(const half4*)(out + base);  // residual+bias already there
    float4 o;
    o.x = fmaf(acc.x, rd, (float)rv[0]);
    o.y = fmaf(acc.y, rd, (float)rv[1]);
    o.z = fmaf(acc.z, rd, (float)rv[2]);
    o.w = fmaf(acc.w, rd, (float)rv[3]);
    half4 st;
    st[0] = (_Float16)o.x; st[1] = (_Float16)o.y;
    st[2] = (_Float16)o.z; st[3] = (_Float16)o.w;
    *(half4*)(out + base) = st;
    *(float4*)(&sv[pair * HC + lane * 4]) = o;
  }
  __syncthreads();
  if (t < HC) {
    int b = blockIdx.x;
    int g0 = batch[b * 2];
    float s = 0.0f, ss = 0.0f;
#pragma unroll
    for (int w = 0; w < 2; w++) {
      int g = batch[b * 2 + w];
      float v = sv[w * HC + t];
      if (g == g0) {
        s += v;
        ss = fmaf(v, v, ss);
      } else {  // rare graph-straddle: direct atomic
        atomicAdd(&stats[g * HC + t], v);
        atomicAdd(&stats[(NGRAPH + g) * HC + t], v * v);
      }
    }
    parts[(size_t)b * HC + t] = s;
    partq[(size_t)b * HC + t] = ss;
  }
}

__global__ __launch_bounds__(256) void attn_mean_kernel(
    const _Float16* __restrict__ xl, const _Float16* __restrict__ xr,
    const float* __restrict__ att, const int* __restrict__ rowptr,
    const int* __restrict__ colA, const float* __restrict__ res16,
    float* __restrict__ out16) {
  __shared__ float red[2][44][5];
  int t = threadIdx.x;
  int pair = t >> 7;
  int wvp = (t >> 6) & 1;
  int lane = t & 63;
  int node = blockIdx.x * 2 + pair;   // grid = N/2 exactly
  int L = (lane < 44) ? lane : 0;     // lanes 44..63 ride along (zeroed later)
  const float4 av = *(const float4*)(att + L * 4);
  size_t base = (size_t)node * HC + L * 4;
  const float4 xrv = h4f(xr + base);
  float d = 0.0f;
  float4 acc = make_float4(0.f, 0.f, 0.f, 0.f);
  {
    ATTN_HALF_BODY(L * 4)
  }
  if (wvp == 1 && lane < 44) {
    red[pair][lane][0] = d;
    red[pair][lane][1] = acc.x; red[pair][lane][2] = acc.y;
    red[pair][lane][3] = acc.z; red[pair][lane][4] = acc.w;
  }
  __syncthreads();
  if (wvp == 0) {
    if (lane < 44) {
      d += red[pair][lane][0];
      acc.x += red[pair][lane][1]; acc.y += red[pair][lane][2];
      acc.z += red[pair][lane][3]; acc.w += red[pair][lane][4];
    }
    float rd = 1.0f / (d + 1e-16f);
    float4 o;
    o.x = (lane < 44) ? acc.x * rd : 0.0f;
    o.y = (lane < 44) ? acc.y * rd : 0.0f;
    o.z = (lane < 44) ? acc.z * rd : 0.0f;
    o.w = (lane < 44) ? acc.w * rd : 0.0f;
#pragma unroll
    for (int w = 4; w <= 32; w <<= 1) {
      o.x += __shfl_xor(o.x, w);
      o.y += __shfl_xor(o.y, w);
      o.z += __shfl_xor(o.z, w);
      o.w += __shfl_xor(o.w, w);
    }
    if (lane < 4) {
      const float* rp = res16 + (size_t)node * 16 + lane * 4;
      float4 r = *(const float4*)rp;
      float4 ov;
      ov.x = fmaxf(fmaf(o.x, 1.0f / 11.0f, r.x), 0.0f);
      ov.y = fmaxf(fmaf(o.y, 1.0f / 11.0f, r.y), 0.0f);
      ov.z = fmaxf(fmaf(o.z, 1.0f / 11.0f, r.z), 0.0f);
      ov.w = fmaxf(fmaf(o.w, 1.0f / 11.0f, r.w), 0.0f);
      *(float4*)(out16 + (size_t)node * 16 + lane * 4) = ov;
    }
  }
}

// =====================================================================
// res16 = normApply(h) @ c5_Wres(176x16) + c5_b   (norm+relu fused in
// load; h is fp16 trunk)
// =====================================================================
__global__ __launch_bounds__(256) void res16_kernel(const _Float16* __restrict__ h,
                                                    const float* __restrict__ scsh,
                                                    const int* __restrict__ batch,
                                                    const float* __restrict__ Wres,
                                                    const float* __restrict__ b16,
                                                    float* __restrict__ res16) {
  __shared__ float Ws[176 * 16];
  __shared__ float hs[16 * 176];
  int t = threadIdx.x;
  for (int i = t; i < 176 * 16; i += 256) Ws[i] = Wres[i];
  int n0 = blockIdx.x * 16;
  for (int i = t; i < 16 * 176; i += 256) {
    int row = i / 176, k = i - row * 176;
    int g = batch[n0 + row];
    float v = (float)h[(size_t)n0 * HC + i];
    hs[i] = fmaxf(fmaf(v, scsh[g * HC + k], scsh[(NGRAPH + g) * HC + k]), 0.0f);
  }
  __syncthreads();
  int tx = t & 15, ty = t >> 4;
  float acc = b16[tx];
  for (int k = 0; k < HC; k++) acc = fmaf(hs[ty * HC + k], Ws[k * 16 + tx], acc);
  res16[(size_t)(n0 + ty) * 16 + tx] = acc;
}

// =====================================================================
// Head MLP
// =====================================================================
__global__ __launch_bounds__(256) void head_kernel(
    const float* __restrict__ in16, const float* __restrict__ Wo1,
    const float* __restrict__ bo1, const float* __restrict__ Wo2,
    const float* __restrict__ bo2, const float* __restrict__ Wc,
    const float* __restrict__ bc, float* __restrict__ outp) {
  __shared__ float w1[256], w2[512], wcS[320], b1[16], b2[32], bcS[10];
  int t = threadIdx.x;
  for (int i = t; i < 256; i += 256) w1[i] = Wo1[i];
  for (int i = t; i < 512; i += 256) w2[i] = Wo2[i];
  for (int i = t; i < 320; i += 256) wcS[i] = Wc[i];
  if (t < 16) b1[t] = bo1[t];
  if (t < 32) b2[t] = bo2[t];
  if (t < 10) bcS[t] = bc[t];
  __syncthreads();
  int n = blockIdx.x * 256 + t;
  if (n >= N_NODES) return;
  float x[16];
#pragma unroll
  for (int i = 0; i < 16; i++) x[i] = in16[(size_t)n * 16 + i];
  float o1[16];
#pragma unroll
  for (int j = 0; j < 16; j++) {
    float a = b1[j];
#pragma unroll
    for (int k = 0; k < 16; k++) a = fmaf(x[k], w1[k * 16 + j], a);
    o1[j] = fmaxf(a, 0.0f);
  }
  float o2[32];
#pragma unroll
  for (int j = 0; j < 32; j++) {
    float a = b2[j];
#pragma unroll
    for (int k = 0; k < 16; k++) a = fmaf(o1[k], w2[k * 32 + j], a);
    o2[j] = fmaxf(a, 0.0f);
  }
#pragma unroll
  for (int j = 0; j < 10; j++) {
    float a = bcS[j];
#pragma unroll
    for (int k = 0; k < 32; k++) a = fmaf(o2[k], wcS[k * 10 + j], a);
    outp[(size_t)n * 10 + j] = a;
  }
}

// =====================================================================
extern "C" void kernel_launch(void* const* d_in, const int* in_sizes, int n_in,
                              void* d_out, int out_size, void* d_ws, size_t ws_size,
                              hipStream_t stream) {
  (void)in_sizes; (void)n_in; (void)out_size; (void)ws_size;
  const float* x     = (const float*)d_in[0];
  const int*   ei    = (const int*)d_in[1];
  const int*   srcE  = ei;
  const int*   dstE  = ei + N_EDGES;
  const int*   batch = (const int*)d_in[2];
  const float* W_pre = (const float*)d_in[3];
  const float* b_pre = (const float*)d_in[4];
  const float* gn_w  = (const float*)d_in[5];
  const float* gn_b  = (const float*)d_in[6];
  const float* gn_ms = (const float*)d_in[7];
  const float* cWl   = (const float*)d_in[8];
  const float* cWr   = (const float*)d_in[9];
  const float* cAtt  = (const float*)d_in[10];
  const float* cB    = (const float*)d_in[11];
  const float* cWres = (const float*)d_in[12];
  const float* c5Wl  = (const float*)d_in[13];
  const float* c5Wr  = (const float*)d_in[14];
  const float* c5Att = (const float*)d_in[15];
  const float* c5b   = (const float*)d_in[16];
  const float* c5Wres= (const float*)d_in[17];
  const float* Wo1   = (const float*)d_in[18];
  const float* bo1   = (const float*)d_in[19];
  const float* Wo2   = (const float*)d_in[20];
  const float* bo2   = (const float*)d_in[21];
  const float* Wc    = (const float*)d_in[22];
  const float* bc    = (const float*)d_in[23];

  const size_t FB = (size_t)N_NODES * HC;
  const size_t STB = (size_t)2 * NGRAPH * HC;     // one stats buffer
  const size_t PBOLD = (size_t)12500 * HC;        // legacy parts slot (layout keeper)
  float* ws    = (float*)d_ws;
  float* buf0  = ws;           // trunk h: fp16 storage in fp32-sized slot
  float* buf1  = ws + FB;      // xl: fp16 in lower half; parts in upper half
  float* buf2  = ws + 2 * FB;  // xr: fp16 in lower half; partq in upper half
  float* buf3  = ws + 3 * FB;  // trunk o: fp16 storage
  float* res16 = ws + 4 * FB;
  float* out16 = res16 + (size_t)N_NODES * 16;
  float* stats = out16 + (size_t)N_NODES * 16;         // 5 buffers (zeroed)
  int* deg     = (int*)(stats + 5 * STB);              // zeroed with stats
  int* fill    = deg + N_NODES;                        // zeroed with stats
  float* scsh  = (float*)(fill + N_NODES);
  float* partsOld = scsh + STB;                        // legacy, unused
  _Float16* wph = (_Float16*)(partsOld + 2 * PBOLD);   // 991232 halves
  int* ibase   = (int*)((char*)wph + (size_t)991232 * 2);
  int* cntInt  = ibase;
  int* gstart  = ibase + 64;                           // 65 ints
  int* rowptr  = gstart + 65;
  int* colA    = rowptr + N_NODES + 1;
  int* bsum    = colA + N_EDGES;
  // R15: 25000-block attention partials carved from the unused upper
  // halves of the fp16 xl/xr slots (25000*HC floats = FB/2 exactly).
  float* parts = buf1 + FB / 2;
  float* partq = buf2 + FB / 2;

  const int NB = (N_NODES + 255) / 256;

  // single memset: 5 stats buffers + deg + fill (contiguous)
  hipMemsetAsync(stats, 0, sizeof(float) * 5 * STB + sizeof(int) * 2 * N_NODES, stream);

  prep_kernel<<<(TOT_PAIRS + 255) / 256, 256, 0, stream>>>(W_pre, cWl, cWr, cWres, c5Wl, c5Wr, wph);
  cnt_bsearch_kernel<<<1, 64, 0, stream>>>(batch, cntInt, gstart);
  deg_hist_kernel<<<(N_EDGES + 255) / 256, 256, 0, stream>>>(dstE, deg);
  scan1_kernel<<<NB, 256, 0, stream>>>(deg, bsum);
  scan2_kernel<<<1, 256, 0, stream>>>(bsum, NB);
  scan3_kernel<<<NB, 256, 0, stream>>>(deg, bsum, rowptr);
  scatter_kernel<<<(N_EDGES + 255) / 256, 256, 0, stream>>>(srcE, dstE, rowptr, fill, colA);

  const int PRB = (NGRAPH * NCHUNK * HC + 255) / 256;  // 704 blocks for part_reduce

  // pre: buf0 = fp16(x @ W_pre + b_pre), with fused layer-0 GraphNorm
  // partials (stats computed from fp32 accumulators pre-rounding)
  gemm_mfma_t<2, true, false><<<GX8 * 1 * 8, 256, 0, stream>>>(
      x, N_NODES, IN_F, 4, 1, wph, 0, nullptr, batch,
      b_pre, nullptr, nullptr, buf0, nullptr, nullptr,
      parts, partq, stats, 1);
  part_reduce_kernel<<<PRB, 256, 0, stream>>>(parts, partq, gstart, stats, 128);
  gn_finalize_kernel<<<(NGRAPH * HC + 255) / 256, 256, 0, stream>>>(stats, cntInt, gn_w, gn_b, gn_ms, 0, scsh);

  float* h = buf0;  // raw fp16 trunk; norm applied on the fly by consumers
  float* o = buf3;
  for (int i = 0; i < 4; i++) {
    const _Float16* Wcat_i = wph + PREH + (size_t)(3 * i) * MATH;
    gemm_mfma_t<3, false, true><<<GX8 * 3 * 8, 256, 0, stream>>>(
        h, N_NODES, HC, 6, 3, Wcat_i, MATH, scsh, batch,
        nullptr, nullptr, cB + i * HC, buf1, buf2, o,
        nullptr, nullptr, nullptr, 7);
    float* st = stats + (size_t)(i + 1) * STB;
    attn_concat_kernel<<<NBLK_ATTN, 256, 0, stream>>>((const _Float16*)buf1, (const _Float16*)buf2,
                                                      cAtt + i * HC,
                                                      rowptr, colA, (_Float16*)o, batch, st,
                                                      parts, partq);
    part_reduce_kernel<<<PRB, 256, 0, stream>>>(parts, partq, gstart, st, 2);
    gn_finalize_kernel<<<(NGRAPH * HC + 255) / 256, 256, 0, stream>>>(st, cntInt, gn_w, gn_b, gn_ms, i + 1, scsh);
    float* tmp = h; h = o; o = tmp;
  }

  // conv5 (input = raw fp16 h with scsh row 4 fused in consumers)
  const _Float16* Wc5 = wph + PREH + (size_t)12 * MATH;
  gemm_mfma_t<3, false, true><<<GX8 * 2 * 8, 256, 0, stream>>>(
      h, N_NODES, HC, 6, 2, Wc5, MATH, scsh, batch,
      nullptr, nullptr, nullptr, buf1, buf2, nullptr,
      nullptr, nullptr, nullptr, 3);
  res16_kernel<<<N_NODES / 16, 256, 0, stream>>>((const _Float16*)h, scsh, batch, c5Wres, c5b, res16);
  attn_mean_kernel<<<NBLK_ATTN, 256, 0, stream>>>((const _Float16*)buf1, (const _Float16*)buf2,
                                                  c5Att, rowptr, colA, res16, out16);

  head_kernel<<<NB, 256, 0, stream>>>(out16, Wo1, bo1, Wo2, bo2, Wc, bc, (float*)d_out);
}

// Round 6
// 692.592 us; speedup vs baseline: 1.1503x; 1.1503x over previous
//
#include <hip/hip_runtime.h>
#include <math.h>

#define N_NODES 50000
#define N_EDGES 400000
#define IN_F 128
#define HC 176
#define NGRAPH 64
#define NBLK_ATTN 12500   // N_NODES/4 exactly
#define NCHUNK 16         // stats chunks per graph (atomic spread)
#define SQOFF (NGRAPH * NCHUNK * HC)   // offset of sum-of-squares half

typedef _Float16 half8 __attribute__((ext_vector_type(8)));
typedef _Float16 half4 __attribute__((ext_vector_type(4)));
typedef float floatx4 __attribute__((ext_vector_type(4)));

__device__ inline float4 h4f(const _Float16* p) {
  half4 h = *(const half4*)p;
  return make_float4((float)h[0], (float)h[1], (float)h[2], (float)h[3]);
}

// wave-uniform row pointer: force the gathered row index into an SGPR so
// the per-edge address math is scalar (global_load saddr + voffset).
__device__ inline const _Float16* urow(const _Float16* p, int c) {
  return p + (size_t)(unsigned)__builtin_amdgcn_readfirstlane(c) * HC;
}

// =====================================================================
// Packed split-fp16 weights in MFMA B-fragment order.
// =====================================================================
#define PREH 45056   // 4*11*2*512 halves
#define MATH 67584   // 6*11*2*512 halves
#define TOT_PAIRS 495616  // 22528 + 14*33792
#define KCBYTES 22528     // bytes per kc chunk (11*2*512*2)
#define GX8 49            // row-tile groups of 8 (49*8=392 >= 391 tiles)

__global__ void prep_kernel(const float* __restrict__ Wpre,
                            const float* __restrict__ cWl, const float* __restrict__ cWr,
                            const float* __restrict__ cWres,
                            const float* __restrict__ c5Wl, const float* __restrict__ c5Wr,
                            _Float16* __restrict__ wp) {
  int gid = blockIdx.x * 256 + threadIdx.x;
  if (gid >= TOT_PAIRS) return;
  int mat, idx;
  if (gid < 22528) { mat = 0; idx = gid; }
  else { int g = gid - 22528; mat = 1 + g / 33792; idx = g % 33792; }
  int kc = idx / 5632;
  int rem = idx - kc * 5632;
  int ct = rem / 512;
  int li = rem - ct * 512;
  int lane = li >> 3, j = li & 7;
  int k = kc * 32 + ((lane >> 4) << 3) + j;
  int col = ct * 16 + (lane & 15);
  const float* src; int Ksrc; size_t base;
  if (mat == 0) { src = Wpre; Ksrc = 128; base = 0; }
  else if (mat <= 12) {
    int lm = mat - 1; int layer = lm / 3; int sub = lm - layer * 3;
    const float* s = (sub == 0) ? cWl : (sub == 1) ? cWr : cWres;
    src = s + (size_t)layer * HC * HC; Ksrc = HC;
    base = PREH + (size_t)lm * MATH;
  } else {
    src = (mat == 13) ? c5Wl : c5Wr; Ksrc = HC;
    base = PREH + (size_t)12 * MATH + (size_t)(mat - 13) * MATH;
  }
  float v = (k < Ksrc) ? src[(size_t)k * HC + col] : 0.0f;
  _Float16 h = (_Float16)v;
  _Float16 l = (_Float16)(v - (float)h);
  size_t o = base + (size_t)(kc * 11 + ct) * 1024 + li;
  wp[o] = h;
  wp[o + 512] = l;
}

// =====================================================================
// Split-fp16 MFMA GEMM with block-level LDS staging of B + XCD swizzle.
// AHALF: A stored fp16 (trunk). halfMask: bit per mat -> fp16 output.
// DOSTATS (pre-GEMM only): GraphNorm partials via chunked atomics into
// stats (R16: parts/partq pipeline deleted). grid.x = GX8 * nmat * 8.
// =====================================================================
template <int MINW, bool DOSTATS, bool AHALF>
__global__ __launch_bounds__(256, MINW) void gemm_mfma_t(
    const float* __restrict__ A, int M, int K, int nkc, int nmat,
    const _Float16* __restrict__ Wp, int matStride,
    const float* __restrict__ scsh, const int* __restrict__ batch,
    const float* __restrict__ bias0, const float* __restrict__ bias1,
    const float* __restrict__ bias2,
    float* __restrict__ out0, float* __restrict__ out1, float* __restrict__ out2,
    float* __restrict__ stats, int halfMask) {
  __shared__ __align__(16) char smem[2 * KCBYTES];
  const int b = blockIdx.x;
  const int grp = b >> 3, sub = b & 7;
  const int mat = grp % nmat;
  const int tile = ((grp / nmat) << 3) | sub;
  if (tile * 128 >= M) return;
  const _Float16* W = Wp + (size_t)mat * matStride;
  float* outp = (mat == 0) ? out0 : (mat == 1) ? out1 : out2;
  const float* bias = (mat == 0) ? bias0 : (mat == 1) ? bias1 : bias2;
  const bool hOut = (halfMask >> mat) & 1;
  const int tid = threadIdx.x;
  const int lane = tid & 63;
  const int wv = tid >> 6;
  const int m16 = lane & 15, quad = lane >> 4;
  const int kb = quad << 3;
  const int rowBase = tile * 128 + wv * 32;
  const int rA0 = min(rowBase + m16, M - 1);
  const int rA1 = min(rowBase + 16 + m16, M - 1);
  const float* ap0 = A + (size_t)rA0 * K + kb;
  const float* ap1 = A + (size_t)rA1 * K + kb;
  const _Float16* hp0 = (const _Float16*)A + (size_t)rA0 * K + kb;
  const _Float16* hp1 = (const _Float16*)A + (size_t)rA1 * K + kb;
  const float* sc0 = nullptr; const float* sh0 = nullptr;
  const float* sc1 = nullptr; const float* sh1 = nullptr;
  if (scsh) {
    int g0 = batch[rA0], g1 = batch[rA1];
    sc0 = scsh + (size_t)g0 * HC + kb;
    sh0 = scsh + (size_t)(NGRAPH + g0) * HC + kb;
    sc1 = scsh + (size_t)g1 * HC + kb;
    sh1 = scsh + (size_t)(NGRAPH + g1) * HC + kb;
  }

  auto stage = [&](int kc, int buf) {
    const char* src = (const char*)W + (size_t)kc * KCBYTES;
    char* dst = smem + buf * KCBYTES;
#pragma unroll
    for (int i = 0; i < 6; i++) {
      int idx = wv * 6 + i;
      if (idx < 22) {
        __builtin_amdgcn_global_load_lds(
            (const __attribute__((address_space(1))) unsigned int*)(src + idx * 1024 + lane * 16),
            (__attribute__((address_space(3))) unsigned int*)(dst + idx * 1024),
            16, 0, 0);
      }
    }
  };

  floatx4 acc0[11], acc1[11];
#pragma unroll
  for (int ct = 0; ct < 11; ct++)
#pragma unroll
    for (int r = 0; r < 4; r++) { acc0[ct][r] = 0.0f; acc1[ct][r] = 0.0f; }

  stage(0, 0);

  for (int kc = 0; kc < nkc; kc++) {
    const int buf = kc & 1;
    __syncthreads();
    if (kc + 1 < nkc) stage(kc + 1, 1 - buf);

    const int koff = kc << 5;
    float va0[8], va1[8];
    if (koff + kb + 8 <= K) {
      if (AHALF) {
        half8 u = *(const half8*)(hp0 + koff);
        half8 w = *(const half8*)(hp1 + koff);
#pragma unroll
        for (int j = 0; j < 8; j++) { va0[j] = (float)u[j]; va1[j] = (float)w[j]; }
      } else {
        float4 u0 = *(const float4*)(ap0 + koff);
        float4 u1 = *(const float4*)(ap0 + koff + 4);
        float4 w0 = *(const float4*)(ap1 + koff);
        float4 w1 = *(const float4*)(ap1 + koff + 4);
        va0[0] = u0.x; va0[1] = u0.y; va0[2] = u0.z; va0[3] = u0.w;
        va0[4] = u1.x; va0[5] = u1.y; va0[6] = u1.z; va0[7] = u1.w;
        va1[0] = w0.x; va1[1] = w0.y; va1[2] = w0.z; va1[3] = w0.w;
        va1[4] = w1.x; va1[5] = w1.y; va1[6] = w1.z; va1[7] = w1.w;
      }
      if (scsh) {
        float s0[8], h0[8], s1[8], h1[8];
        float4 t;
        t = *(const float4*)(sc0 + koff);     s0[0]=t.x; s0[1]=t.y; s0[2]=t.z; s0[3]=t.w;
        t = *(const float4*)(sc0 + koff + 4); s0[4]=t.x; s0[5]=t.y; s0[6]=t.z; s0[7]=t.w;
        t = *(const float4*)(sh0 + koff);     h0[0]=t.x; h0[1]=t.y; h0[2]=t.z; h0[3]=t.w;
        t = *(const float4*)(sh0 + koff + 4); h0[4]=t.x; h0[5]=t.y; h0[6]=t.z; h0[7]=t.w;
        t = *(const float4*)(sc1 + koff);     s1[0]=t.x; s1[1]=t.y; s1[2]=t.z; s1[3]=t.w;
        t = *(const float4*)(sc1 + koff + 4); s1[4]=t.x; s1[5]=t.y; s1[6]=t.z; s1[7]=t.w;
        t = *(const float4*)(sh1 + koff);     h1[0]=t.x; h1[1]=t.y; h1[2]=t.z; h1[3]=t.w;
        t = *(const float4*)(sh1 + koff + 4); h1[4]=t.x; h1[5]=t.y; h1[6]=t.z; h1[7]=t.w;
#pragma unroll
        for (int j = 0; j < 8; j++) {
          va0[j] = fmaxf(fmaf(va0[j], s0[j], h0[j]), 0.0f);
          va1[j] = fmaxf(fmaf(va1[j], s1[j], h1[j]), 0.0f);
        }
      }
    } else {
#pragma unroll
      for (int j = 0; j < 8; j++) { va0[j] = 0.0f; va1[j] = 0.0f; }
    }
    half8 ah0, al0, ah1, al1;
#pragma unroll
    for (int j = 0; j < 8; j++) {
      _Float16 h = (_Float16)va0[j];
      ah0[j] = h; al0[j] = (_Float16)(va0[j] - (float)h);
      _Float16 g = (_Float16)va1[j];
      ah1[j] = g; al1[j] = (_Float16)(va1[j] - (float)g);
    }
    const char* bbase = smem + buf * KCBYTES + lane * 16;
#pragma unroll
    for (int ct = 0; ct < 11; ct++) {
      half8 bh = *(const half8*)(bbase + ct * 2048);
      half8 bl = *(const half8*)(bbase + ct * 2048 + 1024);
      acc0[ct] = __builtin_amdgcn_mfma_f32_16x16x32_f16(ah0, bh, acc0[ct], 0, 0, 0);
      acc1[ct] = __builtin_amdgcn_mfma_f32_16x16x32_f16(ah1, bh, acc1[ct], 0, 0, 0);
      acc0[ct] = __builtin_amdgcn_mfma_f32_16x16x32_f16(al0, bh, acc0[ct], 0, 0, 0);
      acc1[ct] = __builtin_amdgcn_mfma_f32_16x16x32_f16(al1, bh, acc1[ct], 0, 0, 0);
      acc0[ct] = __builtin_amdgcn_mfma_f32_16x16x32_f16(ah0, bl, acc0[ct], 0, 0, 0);
      acc1[ct] = __builtin_amdgcn_mfma_f32_16x16x32_f16(ah1, bl, acc1[ct], 0, 0, 0);
    }
  }

  float bv[11];
#pragma unroll
  for (int ct = 0; ct < 11; ct++) bv[ct] = bias ? bias[ct * 16 + m16] : 0.0f;
#pragma unroll
  for (int r = 0; r < 4; r++) {
    int row0 = rowBase + (quad << 2) + r;
    if (row0 < M) {
      if (hOut) {
        _Float16* op = (_Float16*)outp + (size_t)row0 * HC + m16;
#pragma unroll
        for (int ct = 0; ct < 11; ct++) op[ct * 16] = (_Float16)(acc0[ct][r] + bv[ct]);
      } else {
        float* op = outp + (size_t)row0 * HC + m16;
#pragma unroll
        for (int ct = 0; ct < 11; ct++) op[ct * 16] = acc0[ct][r] + bv[ct];
      }
    }
    int row1 = row0 + 16;
    if (row1 < M) {
      if (hOut) {
        _Float16* op = (_Float16*)outp + (size_t)row1 * HC + m16;
#pragma unroll
        for (int ct = 0; ct < 11; ct++) op[ct * 16] = (_Float16)(acc1[ct][r] + bv[ct]);
      } else {
        float* op = outp + (size_t)row1 * HC + m16;
#pragma unroll
        for (int ct = 0; ct < 11; ct++) op[ct * 16] = acc1[ct][r] + bv[ct];
      }
    }
  }

  if (DOSTATS) {
    // ---- fused GraphNorm per-tile partials (128 rows, <=2 graphs) ----
    // R16: chunked atomics into stats (no parts/partq arrays).
    int gTile = batch[tile * 128];  // tile*128 < M guaranteed
    int lastRow = min(tile * 128 + 127, M - 1);
    bool straddle = (batch[lastRow] != gTile);
    bool validR[8]; bool otherR[8];
#pragma unroll
    for (int r = 0; r < 4; r++) {
      int row0 = rowBase + (quad << 2) + r;
      validR[r] = (row0 < M);
      otherR[r] = validR[r] && (batch[min(row0, M - 1)] != gTile);
      int row1 = row0 + 16;
      validR[4 + r] = (row1 < M);
      otherR[4 + r] = validR[4 + r] && (batch[min(row1, M - 1)] != gTile);
    }
    __syncthreads();  // staging LDS no longer needed; reuse for reduction
    float* red = (float*)smem;  // [4][11][16][4]
#pragma unroll
    for (int ct = 0; ct < 11; ct++) {
      float sA = 0.f, qA = 0.f, sB = 0.f, qB = 0.f;
#pragma unroll
      for (int r = 0; r < 4; r++) {
        if (validR[r]) {
          float v = acc0[ct][r] + bv[ct];
          if (otherR[r]) { sB += v; qB = fmaf(v, v, qB); }
          else           { sA += v; qA = fmaf(v, v, qA); }
        }
        if (validR[4 + r]) {
          float v = acc1[ct][r] + bv[ct];
          if (otherR[4 + r]) { sB += v; qB = fmaf(v, v, qB); }
          else               { sA += v; qA = fmaf(v, v, qA); }
        }
      }
      sA += __shfl_xor(sA, 16); sA += __shfl_xor(sA, 32);
      qA += __shfl_xor(qA, 16); qA += __shfl_xor(qA, 32);
      sB += __shfl_xor(sB, 16); sB += __shfl_xor(sB, 32);
      qB += __shfl_xor(qB, 16); qB += __shfl_xor(qB, 32);
      if (quad == 0) {
        float* slot = red + (((wv * 11 + ct) * 16 + m16) << 2);
        slot[0] = sA; slot[1] = qA; slot[2] = sB; slot[3] = qB;
      }
    }
    __syncthreads();
    if (tid < HC) {
      int col = tid;
      float sA = 0.f, qA = 0.f, sB = 0.f, qB = 0.f;
#pragma unroll
      for (int w = 0; w < 4; w++) {
        float* slot = red + (((w * 11 + col / 16) * 16 + (col & 15)) << 2);
        sA += slot[0]; qA += slot[1]; sB += slot[2]; qB += slot[3];
      }
      int chunk = tile & (NCHUNK - 1);
      atomicAdd(&stats[(gTile * NCHUNK + chunk) * HC + col], sA);
      atomicAdd(&stats[SQOFF + (gTile * NCHUNK + chunk) * HC + col], qA);
      if (straddle) {
        int g2 = batch[lastRow];
        atomicAdd(&stats[(g2 * NCHUNK + chunk) * HC + col], sB);
        atomicAdd(&stats[SQOFF + (g2 * NCHUNK + chunk) * HC + col], qB);
      }
    }
  }
}

// =====================================================================
// GraphNorm finalize: sum the NCHUNK atomic chunks, emit scale/shift.
// =====================================================================
__global__ void gn_finalize_kernel(const float* __restrict__ stats, const int* __restrict__ cntInt,
                                   const float* __restrict__ gnw, const float* __restrict__ gnb,
                                   const float* __restrict__ gnms, int row,
                                   float* __restrict__ scsh) {
  int i = blockIdx.x * 256 + threadIdx.x;
  if (i >= NGRAPH * HC) return;
  int g = i / HC, f = i - g * HC;
  float sm = 0.f, sq = 0.f;
#pragma unroll
  for (int c = 0; c < NCHUNK; c++) {
    sm += stats[(g * NCHUNK + c) * HC + f];
    sq += stats[SQOFF + (g * NCHUNK + c) * HC + f];
  }
  float cnt = fmaxf((float)cntInt[g], 1.0f);
  float m = sm / cnt;
  float msq = sq / cnt;
  float ms = gnms[row * HC + f];
  float var = msq - m * m * ms * (2.0f - ms);
  float w = gnw[row * HC + f], b = gnb[row * HC + f];
  float scale = w / sqrtf(var + 1e-5f);
  float shift = b - scale * ms * m;
  scsh[i] = scale;
  scsh[NGRAPH * HC + i] = shift;
}

// =====================================================================
// Per-graph counts + start offsets via binary search (batch sorted).
// =====================================================================
__global__ void cnt_bsearch_kernel(const int* __restrict__ batch, int* __restrict__ cntInt,
                                   int* __restrict__ gstart) {
  int g = threadIdx.x;
  if (g >= NGRAPH) return;
  auto lb = [&](int v) {
    int lo = 0, hi = N_NODES;
    while (lo < hi) {
      int mid = (lo + hi) >> 1;
      if (batch[mid] < v) lo = mid + 1; else hi = mid;
    }
    return lo;
  };
  int a = lb(g), b = lb(g + 1);
  cntInt[g] = b - a;
  gstart[g] = a;
  if (g == NGRAPH - 1) gstart[NGRAPH] = N_NODES;
}

// =====================================================================
// CSR build by destination
// =====================================================================
__global__ void deg_hist_kernel(const int* __restrict__ dstE, int* __restrict__ deg) {
  int e = blockIdx.x * 256 + threadIdx.x;
  if (e < N_EDGES) atomicAdd(&deg[dstE[e]], 1);
}

__global__ void scan1_kernel(const int* __restrict__ deg, int* __restrict__ bsum) {
  __shared__ int sd[256];
  int i = blockIdx.x * 256 + threadIdx.x;
  sd[threadIdx.x] = (i < N_NODES) ? deg[i] : 0;
  __syncthreads();
  for (int s = 128; s > 0; s >>= 1) {
    if (threadIdx.x < s) sd[threadIdx.x] += sd[threadIdx.x + s];
    __syncthreads();
  }
  if (threadIdx.x == 0) bsum[blockIdx.x] = sd[0];
}

__global__ void scan2_kernel(int* __restrict__ bsum, int nb) {
  __shared__ int sd[256];
  int t = threadIdx.x;
  int v0 = (t < nb) ? bsum[t] : 0;
  sd[t] = v0;
  __syncthreads();
  for (int s = 1; s < 256; s <<= 1) {
    int v = (t >= s) ? sd[t - s] : 0;
    __syncthreads();
    sd[t] += v;
    __syncthreads();
  }
  if (t < nb) bsum[t] = sd[t] - v0;  // exclusive
}

__global__ void scan3_kernel(const int* __restrict__ deg, const int* __restrict__ bsum,
                             int* __restrict__ rowptr) {
  __shared__ int sd[256];
  int i = blockIdx.x * 256 + threadIdx.x;
  int t = threadIdx.x;
  int d = (i < N_NODES) ? deg[i] : 0;
  sd[t] = d;
  __syncthreads();
  for (int s = 1; s < 256; s <<= 1) {
    int v = (t >= s) ? sd[t - s] : 0;
    __syncthreads();
    sd[t] += v;
    __syncthreads();
  }
  if (i < N_NODES) rowptr[i] = bsum[blockIdx.x] + sd[t] - d;
  if (i == 0) rowptr[N_NODES] = N_EDGES;
}

__global__ void scatter_kernel(const int* __restrict__ srcE, const int* __restrict__ dstE,
                               const int* __restrict__ rowptr, int* __restrict__ fill,
                               int* __restrict__ colA) {
  int e = blockIdx.x * 256 + threadIdx.x;
  if (e < N_EDGES) {
    int d = dstE[e];
    int pos = rowptr[d] + atomicAdd(&fill[d], 1);
    colA[pos] = srcE[e];
  }
}

// =====================================================================
// GATv2 attention. fp16 xl/xr/trunk; R4 structure (1 wave/node, 2-deep
// pipeline — proven optimum vs 4-deep ILP and 2-wave TLP variants).
// R16: (a) gather row index scalarized via readfirstlane, (b) GraphNorm
// partials via chunked atomics (parts/partq pipeline deleted), (c) out
// RMW read hoisted above the edge loop.
// =====================================================================
#define AEDGE(V, D, ACC)                                                      \
  do {                                                                        \
    float e0 = (V).x + xrv.x; e0 = fmaxf(e0, 0.2f * e0);                      \
    float e1 = (V).y + xrv.y; e1 = fmaxf(e1, 0.2f * e1);                      \
    float e2 = (V).z + xrv.z; e2 = fmaxf(e2, 0.2f * e2);                      \
    float e3 = (V).w + xrv.w; e3 = fmaxf(e3, 0.2f * e3);                      \
    float p = fmaf(e3, av.w, fmaf(e2, av.z, fmaf(e1, av.y, e0 * av.x)));      \
    p += __shfl_xor(p, 1);                                                    \
    p += __shfl_xor(p, 2);                                                    \
    float pp = __expf(p);                                                     \
    (D) += pp;                                                                \
    (ACC).x = fmaf(pp, (V).x, (ACC).x);                                       \
    (ACC).y = fmaf(pp, (V).y, (ACC).y);                                       \
    (ACC).z = fmaf(pp, (V).z, (ACC).z);                                       \
    (ACC).w = fmaf(pp, (V).w, (ACC).w);                                       \
  } while (0)

#define ATTN_BODY(XLL)                                                        \
  int start = rowptr[node], end = rowptr[node + 1];                           \
  float d = 0.0f, dB = 0.0f;                                                  \
  float4 acc = make_float4(0.f, 0.f, 0.f, 0.f);                               \
  float4 accB = make_float4(0.f, 0.f, 0.f, 0.f);                              \
  float4 p1, p2;                                                              \
  if (start < end)     p1 = h4f(urow(xl, colA[start]) + (XLL));               \
  if (start + 1 < end) p2 = h4f(urow(xl, colA[start + 1]) + (XLL));           \
  {                                                                           \
    float4 svv = h4f(xl + base);  /* self-loop */                             \
    AEDGE(svv, d, acc);                                                       \
  }                                                                           \
  int j = start;                                                              \
  for (; j + 3 < end; j += 2) {                                               \
    float4 n1 = h4f(urow(xl, colA[j + 2]) + (XLL));                           \
    float4 n2 = h4f(urow(xl, colA[j + 3]) + (XLL));                           \
    AEDGE(p1, d, acc);                                                        \
    AEDGE(p2, dB, accB);                                                      \
    p1 = n1; p2 = n2;                                                         \
  }                                                                           \
  if (j < end)     AEDGE(p1, d, acc);                                         \
  if (j + 1 < end) AEDGE(p2, dB, accB);                                       \
  if (j + 2 < end) {                                                          \
    float4 n1 = h4f(urow(xl, colA[j + 2]) + (XLL));                           \
    AEDGE(n1, d, acc);                                                        \
  }                                                                           \
  d += dB;                                                                    \
  acc.x += accB.x; acc.y += accB.y; acc.z += accB.z; acc.w += accB.w;

__global__ __launch_bounds__(256) void attn_concat_kernel(
    const _Float16* __restrict__ xl, const _Float16* __restrict__ xr,
    const float* __restrict__ att, const int* __restrict__ rowptr,
    const int* __restrict__ colA, _Float16* __restrict__ out,
    const int* __restrict__ batch, float* __restrict__ stats) {
  __shared__ float sv[4 * HC];
  int t = threadIdx.x;
  int node = blockIdx.x * 4 + (t >> 6);
  int lane = t & 63;
  if (lane < 44) {  // node < N always (grid = N/4 exactly)
    const float4 av = *(const float4*)(att + lane * 4);
    size_t base = (size_t)node * HC + lane * 4;
    const float4 xrv = h4f(xr + base);
    half4 rv = *(const half4*)(out + base);  // residual+bias (hoisted read)
    ATTN_BODY(lane * 4)
    float rd = 1.0f / (d + 1e-16f);
    float4 o;
    o.x = fmaf(acc.x, rd, (float)rv[0]);
    o.y = fmaf(acc.y, rd, (float)rv[1]);
    o.z = fmaf(acc.z, rd, (float)rv[2]);
    o.w = fmaf(acc.w, rd, (float)rv[3]);
    half4 st;
    st[0] = (_Float16)o.x; st[1] = (_Float16)o.y;
    st[2] = (_Float16)o.z; st[3] = (_Float16)o.w;
    *(half4*)(out + base) = st;
    *(float4*)(&sv[(t >> 6) * HC + lane * 4]) = o;
  }
  __syncthreads();
  if (t < HC) {
    int b = blockIdx.x;
    int chunk = b & (NCHUNK - 1);
    int g0 = batch[b * 4];
    float s = 0.0f, ss = 0.0f;
    float sB = 0.0f, ssB = 0.0f;
    int gB = -1;
#pragma unroll
    for (int w = 0; w < 4; w++) {
      int g = batch[b * 4 + w];
      float v = sv[w * HC + t];
      if (g == g0) {
        s += v;
        ss = fmaf(v, v, ss);
      } else {  // rare graph-straddle
        gB = g; sB += v; ssB = fmaf(v, v, ssB);
      }
    }
    atomicAdd(&stats[(g0 * NCHUNK + chunk) * HC + t], s);
    atomicAdd(&stats[SQOFF + (g0 * NCHUNK + chunk) * HC + t], ss);
    if (gB >= 0) {
      atomicAdd(&stats[(gB * NCHUNK + chunk) * HC + t], sB);
      atomicAdd(&stats[SQOFF + (gB * NCHUNK + chunk) * HC + t], ssB);
    }
  }
}

__global__ __launch_bounds__(256) void attn_mean_kernel(
    const _Float16* __restrict__ xl, const _Float16* __restrict__ xr,
    const float* __restrict__ att, const int* __restrict__ rowptr,
    const int* __restrict__ colA, const float* __restrict__ res16,
    float* __restrict__ out16) {
  int t = threadIdx.x;
  int node = blockIdx.x * 4 + (t >> 6);
  int lane = t & 63;
  if (node >= N_NODES) return;
  int L = (lane < 44) ? lane : 0;  // lanes 44..63 ride along (zeroed later)
  const float4 av = *(const float4*)(att + L * 4);
  size_t base = (size_t)node * HC + L * 4;
  const float4 xrv = h4f(xr + base);
  ATTN_BODY(L * 4)
  float rd = 1.0f / (d + 1e-16f);
  float4 o;
  o.x = (lane < 44) ? acc.x * rd : 0.0f;
  o.y = (lane < 44) ? acc.y * rd : 0.0f;
  o.z = (lane < 44) ? acc.z * rd : 0.0f;
  o.w = (lane < 44) ? acc.w * rd : 0.0f;
#pragma unroll
  for (int w = 4; w <= 32; w <<= 1) {
    o.x += __shfl_xor(o.x, w);
    o.y += __shfl_xor(o.y, w);
    o.z += __shfl_xor(o.z, w);
    o.w += __shfl_xor(o.w, w);
  }
  if (lane < 4) {
    const float* rp = res16 + (size_t)node * 16 + lane * 4;
    float4 r = *(const float4*)rp;
    float4 ov;
    ov.x = fmaxf(fmaf(o.x, 1.0f / 11.0f, r.x), 0.0f);
    ov.y = fmaxf(fmaf(o.y, 1.0f / 11.0f, r.y), 0.0f);
    ov.z = fmaxf(fmaf(o.z, 1.0f / 11.0f, r.z), 0.0f);
    ov.w = fmaxf(fmaf(o.w, 1.0f / 11.0f, r.w), 0.0f);
    *(float4*)(out16 + (size_t)node * 16 + lane * 4) = ov;
  }
}

// =====================================================================
// res16 = normApply(h) @ c5_Wres(176x16) + c5_b   (norm+relu fused in
// load; h is fp16 trunk)
// =====================================================================
__global__ __launch_bounds__(256) void res16_kernel(const _Float16* __restrict__ h,
                                                    const float* __restrict__ scsh,
                                                    const int* __restrict__ batch,
                                                    const float* __restrict__ Wres,
                                                    const float* __restrict__ b16,
                                                    float* __restrict__ res16) {
  __shared__ float Ws[176 * 16];
  __shared__ float hs[16 * 176];
  int t = threadIdx.x;
  for (int i = t; i < 176 * 16; i += 256) Ws[i] = Wres[i];
  int n0 = blockIdx.x * 16;
  for (int i = t; i < 16 * 176; i += 256) {
    int row = i / 176, k = i - row * 176;
    int g = batch[n0 + row];
    float v = (float)h[(size_t)n0 * HC + i];
    hs[i] = fmaxf(fmaf(v, scsh[g * HC + k], scsh[(NGRAPH + g) * HC + k]), 0.0f);
  }
  __syncthreads();
  int tx = t & 15, ty = t >> 4;
  float acc = b16[tx];
  for (int k = 0; k < HC; k++) acc = fmaf(hs[ty * HC + k], Ws[k * 16 + tx], acc);
  res16[(size_t)(n0 + ty) * 16 + tx] = acc;
}

// =====================================================================
// Head MLP
// =====================================================================
__global__ __launch_bounds__(256) void head_kernel(
    const float* __restrict__ in16, const float* __restrict__ Wo1,
    const float* __restrict__ bo1, const float* __restrict__ Wo2,
    const float* __restrict__ bo2, const float* __restrict__ Wc,
    const float* __restrict__ bc, float* __restrict__ outp) {
  __shared__ float w1[256], w2[512], wcS[320], b1[16], b2[32], bcS[10];
  int t = threadIdx.x;
  for (int i = t; i < 256; i += 256) w1[i] = Wo1[i];
  for (int i = t; i < 512; i += 256) w2[i] = Wo2[i];
  for (int i = t; i < 320; i += 256) wcS[i] = Wc[i];
  if (t < 16) b1[t] = bo1[t];
  if (t < 32) b2[t] = bo2[t];
  if (t < 10) bcS[t] = bc[t];
  __syncthreads();
  int n = blockIdx.x * 256 + t;
  if (n >= N_NODES) return;
  float x[16];
#pragma unroll
  for (int i = 0; i < 16; i++) x[i] = in16[(size_t)n * 16 + i];
  float o1[16];
#pragma unroll
  for (int j = 0; j < 16; j++) {
    float a = b1[j];
#pragma unroll
    for (int k = 0; k < 16; k++) a = fmaf(x[k], w1[k * 16 + j], a);
    o1[j] = fmaxf(a, 0.0f);
  }
  float o2[32];
#pragma unroll
  for (int j = 0; j < 32; j++) {
    float a = b2[j];
#pragma unroll
    for (int k = 0; k < 16; k++) a = fmaf(o1[k], w2[k * 32 + j], a);
    o2[j] = fmaxf(a, 0.0f);
  }
#pragma unroll
  for (int j = 0; j < 10; j++) {
    float a = bcS[j];
#pragma unroll
    for (int k = 0; k < 32; k++) a = fmaf(o2[k], wcS[k * 10 + j], a);
    outp[(size_t)n * 10 + j] = a;
  }
}

// =====================================================================
extern "C" void kernel_launch(void* const* d_in, const int* in_sizes, int n_in,
                              void* d_out, int out_size, void* d_ws, size_t ws_size,
                              hipStream_t stream) {
  (void)in_sizes; (void)n_in; (void)out_size; (void)ws_size;
  const float* x     = (const float*)d_in[0];
  const int*   ei    = (const int*)d_in[1];
  const int*   srcE  = ei;
  const int*   dstE  = ei + N_EDGES;
  const int*   batch = (const int*)d_in[2];
  const float* W_pre = (const float*)d_in[3];
  const float* b_pre = (const float*)d_in[4];
  const float* gn_w  = (const float*)d_in[5];
  const float* gn_b  = (const float*)d_in[6];
  const float* gn_ms = (const float*)d_in[7];
  const float* cWl   = (const float*)d_in[8];
  const float* cWr   = (const float*)d_in[9];
  const float* cAtt  = (const float*)d_in[10];
  const float* cB    = (const float*)d_in[11];
  const float* cWres = (const float*)d_in[12];
  const float* c5Wl  = (const float*)d_in[13];
  const float* c5Wr  = (const float*)d_in[14];
  const float* c5Att = (const float*)d_in[15];
  const float* c5b   = (const float*)d_in[16];
  const float* c5Wres= (const float*)d_in[17];
  const float* Wo1   = (const float*)d_in[18];
  const float* bo1   = (const float*)d_in[19];
  const float* Wo2   = (const float*)d_in[20];
  const float* bo2   = (const float*)d_in[21];
  const float* Wc    = (const float*)d_in[22];
  const float* bc    = (const float*)d_in[23];

  const size_t FB = (size_t)N_NODES * HC;
  const size_t STB2 = (size_t)2 * NGRAPH * NCHUNK * HC;  // chunked stats buffer
  float* ws    = (float*)d_ws;
  float* buf0  = ws;           // trunk h: fp16 storage in fp32-sized slot
  float* buf1  = ws + FB;      // xl: fp16 storage
  float* buf2  = ws + 2 * FB;  // xr: fp16 storage
  float* buf3  = ws + 3 * FB;  // trunk o: fp16 storage
  float* res16 = ws + 4 * FB;
  float* out16 = res16 + (size_t)N_NODES * 16;
  float* stats2 = out16 + (size_t)N_NODES * 16;        // 5 chunked buffers (zeroed)
  int* deg     = (int*)(stats2 + 5 * STB2);            // zeroed with stats
  int* fill    = deg + N_NODES;                        // zeroed with stats
  float* scsh  = (float*)(fill + N_NODES);
  _Float16* wph = (_Float16*)(scsh + (size_t)2 * NGRAPH * HC);  // 991232 halves
  int* ibase   = (int*)((char*)wph + (size_t)991232 * 2);
  int* cntInt  = ibase;
  int* gstart  = ibase + 64;                           // 65 ints
  int* rowptr  = gstart + 65;
  int* colA    = rowptr + N_NODES + 1;
  int* bsum    = colA + N_EDGES;

  const int NB = (N_NODES + 255) / 256;

  // single memset: 5 chunked stats buffers + deg + fill (contiguous)
  hipMemsetAsync(stats2, 0, sizeof(float) * 5 * STB2 + sizeof(int) * 2 * N_NODES, stream);

  prep_kernel<<<(TOT_PAIRS + 255) / 256, 256, 0, stream>>>(W_pre, cWl, cWr, cWres, c5Wl, c5Wr, wph);
  cnt_bsearch_kernel<<<1, 64, 0, stream>>>(batch, cntInt, gstart);
  deg_hist_kernel<<<(N_EDGES + 255) / 256, 256, 0, stream>>>(dstE, deg);
  scan1_kernel<<<NB, 256, 0, stream>>>(deg, bsum);
  scan2_kernel<<<1, 256, 0, stream>>>(bsum, NB);
  scan3_kernel<<<NB, 256, 0, stream>>>(deg, bsum, rowptr);
  scatter_kernel<<<(N_EDGES + 255) / 256, 256, 0, stream>>>(srcE, dstE, rowptr, fill, colA);

  // pre: buf0 = fp16(x @ W_pre + b_pre), with fused layer-0 GraphNorm
  // partials via chunked atomics (fp32 accumulators pre-rounding)
  gemm_mfma_t<2, true, false><<<GX8 * 1 * 8, 256, 0, stream>>>(
      x, N_NODES, IN_F, 4, 1, wph, 0, nullptr, batch,
      b_pre, nullptr, nullptr, buf0, nullptr, nullptr,
      stats2, 1);
  gn_finalize_kernel<<<(NGRAPH * HC + 255) / 256, 256, 0, stream>>>(stats2, cntInt, gn_w, gn_b, gn_ms, 0, scsh);

  float* h = buf0;  // raw fp16 trunk; norm applied on the fly by consumers
  float* o = buf3;
  for (int i = 0; i < 4; i++) {
    const _Float16* Wcat_i = wph + PREH + (size_t)(3 * i) * MATH;
    gemm_mfma_t<3, false, true><<<GX8 * 3 * 8, 256, 0, stream>>>(
        h, N_NODES, HC, 6, 3, Wcat_i, MATH, scsh, batch,
        nullptr, nullptr, cB + i * HC, buf1, buf2, o,
        nullptr, 7);
    float* st = stats2 + (size_t)(i + 1) * STB2;
    attn_concat_kernel<<<NBLK_ATTN, 256, 0, stream>>>((const _Float16*)buf1, (const _Float16*)buf2,
                                                      cAtt + i * HC,
                                                      rowptr, colA, (_Float16*)o, batch, st);
    gn_finalize_kernel<<<(NGRAPH * HC + 255) / 256, 256, 0, stream>>>(st, cntInt, gn_w, gn_b, gn_ms, i + 1, scsh);
    float* tmp = h; h = o; o = tmp;
  }

  // conv5 (input = raw fp16 h with scsh row 4 fused in consumers)
  const _Float16* Wc5 = wph + PREH + (size_t)12 * MATH;
  gemm_mfma_t<3, false, true><<<GX8 * 2 * 8, 256, 0, stream>>>(
      h, N_NODES, HC, 6, 2, Wc5, MATH, scsh, batch,
      nullptr, nullptr, nullptr, buf1, buf2, nullptr,
      nullptr, 3);
  res16_kernel<<<N_NODES / 16, 256, 0, stream>>>((const _Float16*)h, scsh, batch, c5Wres, c5b, res16);
  attn_mean_kernel<<<(N_NODES + 3) / 4, 256, 0, stream>>>((const _Float16*)buf1, (const _Float16*)buf2,
                                                          c5Att, rowptr, colA, res16, out16);

  head_kernel<<<NB, 256, 0, stream>>>(out16, Wo1, bo1, Wo2, bo2, Wc, bc, (float*)d_out);
}

// Round 7
// 641.548 us; speedup vs baseline: 1.2418x; 1.0796x over previous
//
#include <hip/hip_runtime.h>
#include <math.h>

#define N_NODES 50000
#define N_EDGES 400000
#define IN_F 128
#define HC 176
#define NGRAPH 64
#define NBLK_ATTN 12500   // N_NODES/4 exactly
#define NCHUNK 16         // stats chunks per graph (atomic spread)
#define SQOFF (NGRAPH * NCHUNK * HC)   // offset of sum-of-squares half

typedef _Float16 half8 __attribute__((ext_vector_type(8)));
typedef _Float16 half4 __attribute__((ext_vector_type(4)));
typedef _Float16 half2v __attribute__((ext_vector_type(2)));
typedef float floatx4 __attribute__((ext_vector_type(4)));

// wave-uniform row pointer: force the gathered row index into an SGPR so
// the per-edge address math is scalar (global_load saddr + voffset).
__device__ inline const _Float16* urow(const _Float16* p, int c) {
  return p + (size_t)(unsigned)__builtin_amdgcn_readfirstlane(c) * HC;
}

// =====================================================================
// Packed split-fp16 weights in MFMA B-fragment order.
// =====================================================================
#define PREH 45056   // 4*11*2*512 halves
#define MATH 67584   // 6*11*2*512 halves
#define TOT_PAIRS 495616  // 22528 + 14*33792
#define KCBYTES 22528     // bytes per kc chunk (11*2*512*2)
#define GX8 49            // row-tile groups of 8 (49*8=392 >= 391 tiles)

__global__ void prep_kernel(const float* __restrict__ Wpre,
                            const float* __restrict__ cWl, const float* __restrict__ cWr,
                            const float* __restrict__ cWres,
                            const float* __restrict__ c5Wl, const float* __restrict__ c5Wr,
                            _Float16* __restrict__ wp) {
  int gid = blockIdx.x * 256 + threadIdx.x;
  if (gid >= TOT_PAIRS) return;
  int mat, idx;
  if (gid < 22528) { mat = 0; idx = gid; }
  else { int g = gid - 22528; mat = 1 + g / 33792; idx = g % 33792; }
  int kc = idx / 5632;
  int rem = idx - kc * 5632;
  int ct = rem / 512;
  int li = rem - ct * 512;
  int lane = li >> 3, j = li & 7;
  int k = kc * 32 + ((lane >> 4) << 3) + j;
  int col = ct * 16 + (lane & 15);
  const float* src; int Ksrc; size_t base;
  if (mat == 0) { src = Wpre; Ksrc = 128; base = 0; }
  else if (mat <= 12) {
    int lm = mat - 1; int layer = lm / 3; int sub = lm - layer * 3;
    const float* s = (sub == 0) ? cWl : (sub == 1) ? cWr : cWres;
    src = s + (size_t)layer * HC * HC; Ksrc = HC;
    base = PREH + (size_t)lm * MATH;
  } else {
    src = (mat == 13) ? c5Wl : c5Wr; Ksrc = HC;
    base = PREH + (size_t)12 * MATH + (size_t)(mat - 13) * MATH;
  }
  float v = (k < Ksrc) ? src[(size_t)k * HC + col] : 0.0f;
  _Float16 h = (_Float16)v;
  _Float16 l = (_Float16)(v - (float)h);
  size_t o = base + (size_t)(kc * 11 + ct) * 1024 + li;
  wp[o] = h;
  wp[o + 512] = l;
}

// =====================================================================
// Split-fp16 MFMA GEMM with block-level LDS staging of B + XCD swizzle.
// AHALF: A stored fp16 (trunk). halfMask: bit per mat -> fp16 output.
// DOSTATS (pre-GEMM only): GraphNorm partials via chunked atomics into
// stats. grid.x = GX8 * nmat * 8.
// =====================================================================
template <int MINW, bool DOSTATS, bool AHALF>
__global__ __launch_bounds__(256, MINW) void gemm_mfma_t(
    const float* __restrict__ A, int M, int K, int nkc, int nmat,
    const _Float16* __restrict__ Wp, int matStride,
    const float* __restrict__ scsh, const int* __restrict__ batch,
    const float* __restrict__ bias0, const float* __restrict__ bias1,
    const float* __restrict__ bias2,
    float* __restrict__ out0, float* __restrict__ out1, float* __restrict__ out2,
    float* __restrict__ stats, int halfMask) {
  __shared__ __align__(16) char smem[2 * KCBYTES];
  const int b = blockIdx.x;
  const int grp = b >> 3, sub = b & 7;
  const int mat = grp % nmat;
  const int tile = ((grp / nmat) << 3) | sub;
  if (tile * 128 >= M) return;
  const _Float16* W = Wp + (size_t)mat * matStride;
  float* outp = (mat == 0) ? out0 : (mat == 1) ? out1 : out2;
  const float* bias = (mat == 0) ? bias0 : (mat == 1) ? bias1 : bias2;
  const bool hOut = (halfMask >> mat) & 1;
  const int tid = threadIdx.x;
  const int lane = tid & 63;
  const int wv = tid >> 6;
  const int m16 = lane & 15, quad = lane >> 4;
  const int kb = quad << 3;
  const int rowBase = tile * 128 + wv * 32;
  const int rA0 = min(rowBase + m16, M - 1);
  const int rA1 = min(rowBase + 16 + m16, M - 1);
  const float* ap0 = A + (size_t)rA0 * K + kb;
  const float* ap1 = A + (size_t)rA1 * K + kb;
  const _Float16* hp0 = (const _Float16*)A + (size_t)rA0 * K + kb;
  const _Float16* hp1 = (const _Float16*)A + (size_t)rA1 * K + kb;
  const float* sc0 = nullptr; const float* sh0 = nullptr;
  const float* sc1 = nullptr; const float* sh1 = nullptr;
  if (scsh) {
    int g0 = batch[rA0], g1 = batch[rA1];
    sc0 = scsh + (size_t)g0 * HC + kb;
    sh0 = scsh + (size_t)(NGRAPH + g0) * HC + kb;
    sc1 = scsh + (size_t)g1 * HC + kb;
    sh1 = scsh + (size_t)(NGRAPH + g1) * HC + kb;
  }

  auto stage = [&](int kc, int buf) {
    const char* src = (const char*)W + (size_t)kc * KCBYTES;
    char* dst = smem + buf * KCBYTES;
#pragma unroll
    for (int i = 0; i < 6; i++) {
      int idx = wv * 6 + i;
      if (idx < 22) {
        __builtin_amdgcn_global_load_lds(
            (const __attribute__((address_space(1))) unsigned int*)(src + idx * 1024 + lane * 16),
            (__attribute__((address_space(3))) unsigned int*)(dst + idx * 1024),
            16, 0, 0);
      }
    }
  };

  floatx4 acc0[11], acc1[11];
#pragma unroll
  for (int ct = 0; ct < 11; ct++)
#pragma unroll
    for (int r = 0; r < 4; r++) { acc0[ct][r] = 0.0f; acc1[ct][r] = 0.0f; }

  stage(0, 0);

  for (int kc = 0; kc < nkc; kc++) {
    const int buf = kc & 1;
    __syncthreads();
    if (kc + 1 < nkc) stage(kc + 1, 1 - buf);

    const int koff = kc << 5;
    float va0[8], va1[8];
    if (koff + kb + 8 <= K) {
      if (AHALF) {
        half8 u = *(const half8*)(hp0 + koff);
        half8 w = *(const half8*)(hp1 + koff);
#pragma unroll
        for (int j = 0; j < 8; j++) { va0[j] = (float)u[j]; va1[j] = (float)w[j]; }
      } else {
        float4 u0 = *(const float4*)(ap0 + koff);
        float4 u1 = *(const float4*)(ap0 + koff + 4);
        float4 w0 = *(const float4*)(ap1 + koff);
        float4 w1 = *(const float4*)(ap1 + koff + 4);
        va0[0] = u0.x; va0[1] = u0.y; va0[2] = u0.z; va0[3] = u0.w;
        va0[4] = u1.x; va0[5] = u1.y; va0[6] = u1.z; va0[7] = u1.w;
        va1[0] = w0.x; va1[1] = w0.y; va1[2] = w0.z; va1[3] = w0.w;
        va1[4] = w1.x; va1[5] = w1.y; va1[6] = w1.z; va1[7] = w1.w;
      }
      if (scsh) {
        float s0[8], h0[8], s1[8], h1[8];
        float4 t;
        t = *(const float4*)(sc0 + koff);     s0[0]=t.x; s0[1]=t.y; s0[2]=t.z; s0[3]=t.w;
        t = *(const float4*)(sc0 + koff + 4); s0[4]=t.x; s0[5]=t.y; s0[6]=t.z; s0[7]=t.w;
        t = *(const float4*)(sh0 + koff);     h0[0]=t.x; h0[1]=t.y; h0[2]=t.z; h0[3]=t.w;
        t = *(const float4*)(sh0 + koff + 4); h0[4]=t.x; h0[5]=t.y; h0[6]=t.z; h0[7]=t.w;
        t = *(const float4*)(sc1 + koff);     s1[0]=t.x; s1[1]=t.y; s1[2]=t.z; s1[3]=t.w;
        t = *(const float4*)(sc1 + koff + 4); s1[4]=t.x; s1[5]=t.y; s1[6]=t.z; s1[7]=t.w;
        t = *(const float4*)(sh1 + koff);     h1[0]=t.x; h1[1]=t.y; h1[2]=t.z; h1[3]=t.w;
        t = *(const float4*)(sh1 + koff + 4); h1[4]=t.x; h1[5]=t.y; h1[6]=t.z; h1[7]=t.w;
#pragma unroll
        for (int j = 0; j < 8; j++) {
          va0[j] = fmaxf(fmaf(va0[j], s0[j], h0[j]), 0.0f);
          va1[j] = fmaxf(fmaf(va1[j], s1[j], h1[j]), 0.0f);
        }
      }
    } else {
#pragma unroll
      for (int j = 0; j < 8; j++) { va0[j] = 0.0f; va1[j] = 0.0f; }
    }
    half8 ah0, al0, ah1, al1;
#pragma unroll
    for (int j = 0; j < 8; j++) {
      _Float16 h = (_Float16)va0[j];
      ah0[j] = h; al0[j] = (_Float16)(va0[j] - (float)h);
      _Float16 g = (_Float16)va1[j];
      ah1[j] = g; al1[j] = (_Float16)(va1[j] - (float)g);
    }
    const char* bbase = smem + buf * KCBYTES + lane * 16;
#pragma unroll
    for (int ct = 0; ct < 11; ct++) {
      half8 bh = *(const half8*)(bbase + ct * 2048);
      half8 bl = *(const half8*)(bbase + ct * 2048 + 1024);
      acc0[ct] = __builtin_amdgcn_mfma_f32_16x16x32_f16(ah0, bh, acc0[ct], 0, 0, 0);
      acc1[ct] = __builtin_amdgcn_mfma_f32_16x16x32_f16(ah1, bh, acc1[ct], 0, 0, 0);
      acc0[ct] = __builtin_amdgcn_mfma_f32_16x16x32_f16(al0, bh, acc0[ct], 0, 0, 0);
      acc1[ct] = __builtin_amdgcn_mfma_f32_16x16x32_f16(al1, bh, acc1[ct], 0, 0, 0);
      acc0[ct] = __builtin_amdgcn_mfma_f32_16x16x32_f16(ah0, bl, acc0[ct], 0, 0, 0);
      acc1[ct] = __builtin_amdgcn_mfma_f32_16x16x32_f16(ah1, bl, acc1[ct], 0, 0, 0);
    }
  }

  float bv[11];
#pragma unroll
  for (int ct = 0; ct < 11; ct++) bv[ct] = bias ? bias[ct * 16 + m16] : 0.0f;
#pragma unroll
  for (int r = 0; r < 4; r++) {
    int row0 = rowBase + (quad << 2) + r;
    if (row0 < M) {
      if (hOut) {
        _Float16* op = (_Float16*)outp + (size_t)row0 * HC + m16;
#pragma unroll
        for (int ct = 0; ct < 11; ct++) op[ct * 16] = (_Float16)(acc0[ct][r] + bv[ct]);
      } else {
        float* op = outp + (size_t)row0 * HC + m16;
#pragma unroll
        for (int ct = 0; ct < 11; ct++) op[ct * 16] = acc0[ct][r] + bv[ct];
      }
    }
    int row1 = row0 + 16;
    if (row1 < M) {
      if (hOut) {
        _Float16* op = (_Float16*)outp + (size_t)row1 * HC + m16;
#pragma unroll
        for (int ct = 0; ct < 11; ct++) op[ct * 16] = (_Float16)(acc1[ct][r] + bv[ct]);
      } else {
        float* op = outp + (size_t)row1 * HC + m16;
#pragma unroll
        for (int ct = 0; ct < 11; ct++) op[ct * 16] = acc1[ct][r] + bv[ct];
      }
    }
  }

  if (DOSTATS) {
    // ---- fused GraphNorm per-tile partials (128 rows, <=2 graphs) ----
    // chunked atomics into stats (no parts/partq arrays).
    int gTile = batch[tile * 128];  // tile*128 < M guaranteed
    int lastRow = min(tile * 128 + 127, M - 1);
    bool straddle = (batch[lastRow] != gTile);
    bool validR[8]; bool otherR[8];
#pragma unroll
    for (int r = 0; r < 4; r++) {
      int row0 = rowBase + (quad << 2) + r;
      validR[r] = (row0 < M);
      otherR[r] = validR[r] && (batch[min(row0, M - 1)] != gTile);
      int row1 = row0 + 16;
      validR[4 + r] = (row1 < M);
      otherR[4 + r] = validR[4 + r] && (batch[min(row1, M - 1)] != gTile);
    }
    __syncthreads();  // staging LDS no longer needed; reuse for reduction
    float* red = (float*)smem;  // [4][11][16][4]
#pragma unroll
    for (int ct = 0; ct < 11; ct++) {
      float sA = 0.f, qA = 0.f, sB = 0.f, qB = 0.f;
#pragma unroll
      for (int r = 0; r < 4; r++) {
        if (validR[r]) {
          float v = acc0[ct][r] + bv[ct];
          if (otherR[r]) { sB += v; qB = fmaf(v, v, qB); }
          else           { sA += v; qA = fmaf(v, v, qA); }
        }
        if (validR[4 + r]) {
          float v = acc1[ct][r] + bv[ct];
          if (otherR[4 + r]) { sB += v; qB = fmaf(v, v, qB); }
          else               { sA += v; qA = fmaf(v, v, qA); }
        }
      }
      sA += __shfl_xor(sA, 16); sA += __shfl_xor(sA, 32);
      qA += __shfl_xor(qA, 16); qA += __shfl_xor(qA, 32);
      sB += __shfl_xor(sB, 16); sB += __shfl_xor(sB, 32);
      qB += __shfl_xor(qB, 16); qB += __shfl_xor(qB, 32);
      if (quad == 0) {
        float* slot = red + (((wv * 11 + ct) * 16 + m16) << 2);
        slot[0] = sA; slot[1] = qA; slot[2] = sB; slot[3] = qB;
      }
    }
    __syncthreads();
    if (tid < HC) {
      int col = tid;
      float sA = 0.f, qA = 0.f, sB = 0.f, qB = 0.f;
#pragma unroll
      for (int w = 0; w < 4; w++) {
        float* slot = red + (((w * 11 + col / 16) * 16 + (col & 15)) << 2);
        sA += slot[0]; qA += slot[1]; sB += slot[2]; qB += slot[3];
      }
      int chunk = tile & (NCHUNK - 1);
      atomicAdd(&stats[(gTile * NCHUNK + chunk) * HC + col], sA);
      atomicAdd(&stats[SQOFF + (gTile * NCHUNK + chunk) * HC + col], qA);
      if (straddle) {
        int g2 = batch[lastRow];
        atomicAdd(&stats[(g2 * NCHUNK + chunk) * HC + col], sB);
        atomicAdd(&stats[SQOFF + (g2 * NCHUNK + chunk) * HC + col], qB);
      }
    }
  }
}

// =====================================================================
// GraphNorm finalize: sum the NCHUNK atomic chunks, emit scale/shift.
// =====================================================================
__global__ void gn_finalize_kernel(const float* __restrict__ stats, const int* __restrict__ cntInt,
                                   const float* __restrict__ gnw, const float* __restrict__ gnb,
                                   const float* __restrict__ gnms, int row,
                                   float* __restrict__ scsh) {
  int i = blockIdx.x * 256 + threadIdx.x;
  if (i >= NGRAPH * HC) return;
  int g = i / HC, f = i - g * HC;
  float sm = 0.f, sq = 0.f;
#pragma unroll
  for (int c = 0; c < NCHUNK; c++) {
    sm += stats[(g * NCHUNK + c) * HC + f];
    sq += stats[SQOFF + (g * NCHUNK + c) * HC + f];
  }
  float cnt = fmaxf((float)cntInt[g], 1.0f);
  float m = sm / cnt;
  float msq = sq / cnt;
  float ms = gnms[row * HC + f];
  float var = msq - m * m * ms * (2.0f - ms);
  float w = gnw[row * HC + f], b = gnb[row * HC + f];
  float scale = w / sqrtf(var + 1e-5f);
  float shift = b - scale * ms * m;
  scsh[i] = scale;
  scsh[NGRAPH * HC + i] = shift;
}

// =====================================================================
// Per-graph counts + start offsets via binary search (batch sorted).
// =====================================================================
__global__ void cnt_bsearch_kernel(const int* __restrict__ batch, int* __restrict__ cntInt,
                                   int* __restrict__ gstart) {
  int g = threadIdx.x;
  if (g >= NGRAPH) return;
  auto lb = [&](int v) {
    int lo = 0, hi = N_NODES;
    while (lo < hi) {
      int mid = (lo + hi) >> 1;
      if (batch[mid] < v) lo = mid + 1; else hi = mid;
    }
    return lo;
  };
  int a = lb(g), b = lb(g + 1);
  cntInt[g] = b - a;
  gstart[g] = a;
  if (g == NGRAPH - 1) gstart[NGRAPH] = N_NODES;
}

// =====================================================================
// CSR build by destination
// =====================================================================
__global__ void deg_hist_kernel(const int* __restrict__ dstE, int* __restrict__ deg) {
  int e = blockIdx.x * 256 + threadIdx.x;
  if (e < N_EDGES) atomicAdd(&deg[dstE[e]], 1);
}

__global__ void scan1_kernel(const int* __restrict__ deg, int* __restrict__ bsum) {
  __shared__ int sd[256];
  int i = blockIdx.x * 256 + threadIdx.x;
  sd[threadIdx.x] = (i < N_NODES) ? deg[i] : 0;
  __syncthreads();
  for (int s = 128; s > 0; s >>= 1) {
    if (threadIdx.x < s) sd[threadIdx.x] += sd[threadIdx.x + s];
    __syncthreads();
  }
  if (threadIdx.x == 0) bsum[blockIdx.x] = sd[0];
}

__global__ void scan2_kernel(int* __restrict__ bsum, int nb) {
  __shared__ int sd[256];
  int t = threadIdx.x;
  int v0 = (t < nb) ? bsum[t] : 0;
  sd[t] = v0;
  __syncthreads();
  for (int s = 1; s < 256; s <<= 1) {
    int v = (t >= s) ? sd[t - s] : 0;
    __syncthreads();
    sd[t] += v;
    __syncthreads();
  }
  if (t < nb) bsum[t] = sd[t] - v0;  // exclusive
}

__global__ void scan3_kernel(const int* __restrict__ deg, const int* __restrict__ bsum,
                             int* __restrict__ rowptr) {
  __shared__ int sd[256];
  int i = blockIdx.x * 256 + threadIdx.x;
  int t = threadIdx.x;
  int d = (i < N_NODES) ? deg[i] : 0;
  sd[t] = d;
  __syncthreads();
  for (int s = 1; s < 256; s <<= 1) {
    int v = (t >= s) ? sd[t - s] : 0;
    __syncthreads();
    sd[t] += v;
    __syncthreads();
  }
  if (i < N_NODES) rowptr[i] = bsum[blockIdx.x] + sd[t] - d;
  if (i == 0) rowptr[N_NODES] = N_EDGES;
}

__global__ void scatter_kernel(const int* __restrict__ srcE, const int* __restrict__ dstE,
                               const int* __restrict__ rowptr, int* __restrict__ fill,
                               int* __restrict__ colA) {
  int e = blockIdx.x * 256 + threadIdx.x;
  if (e < N_EDGES) {
    int d = dstE[e];
    int pos = rowptr[d] + atomicAdd(&fill[d], 1);
    colA[pos] = srcE[e];
  }
}

// =====================================================================
// GATv2 attention. fp16 xl/xr/trunk; R4 loop structure (1 wave/node,
// 2-deep pipeline — proven optimum). R17: packed-f16 edge math —
// v_pk_add/mul/max for xl+xr and leaky-ReLU, v_dot2_f32_f16 for the
// attention dot (f32 accumulate), v_fma_mix for the acc update (f32
// accumulator fed by raw f16 operands, no explicit cvts). ~1.5x fewer
// VALU issue slots per edge; same bytes, same loop shape.
// =====================================================================
#define AEDGE(V, D, ACC)                                                      \
  do {                                                                        \
    half2v sa = (V).lo + xrl;                                                 \
    half2v sb = (V).hi + xrh;                                                 \
    sa = __builtin_elementwise_max(sa, sa * lk2);                             \
    sb = __builtin_elementwise_max(sb, sb * lk2);                             \
    float p = __builtin_amdgcn_fdot2(                                         \
        sa, ava, __builtin_amdgcn_fdot2(sb, avb, 0.0f, false), false);        \
    p += __shfl_xor(p, 1);                                                    \
    p += __shfl_xor(p, 2);                                                    \
    float pp = __expf(p);                                                     \
    (D) += pp;                                                                \
    (ACC).x = fmaf(pp, (float)(V)[0], (ACC).x);                               \
    (ACC).y = fmaf(pp, (float)(V)[1], (ACC).y);                               \
    (ACC).z = fmaf(pp, (float)(V)[2], (ACC).z);                               \
    (ACC).w = fmaf(pp, (float)(V)[3], (ACC).w);                               \
  } while (0)

#define ATTN_BODY(XLL)                                                        \
  int start = rowptr[node], end = rowptr[node + 1];                           \
  float d = 0.0f, dB = 0.0f;                                                  \
  float4 acc = make_float4(0.f, 0.f, 0.f, 0.f);                               \
  float4 accB = make_float4(0.f, 0.f, 0.f, 0.f);                              \
  half4 p1, p2;                                                               \
  if (start < end)     p1 = *(const half4*)(urow(xl, colA[start]) + (XLL));   \
  if (start + 1 < end) p2 = *(const half4*)(urow(xl, colA[start + 1]) + (XLL)); \
  {                                                                           \
    half4 svv = *(const half4*)(xl + base);  /* self-loop */                  \
    AEDGE(svv, d, acc);                                                       \
  }                                                                           \
  int j = start;                                                              \
  for (; j + 3 < end; j += 2) {                                               \
    half4 n1 = *(const half4*)(urow(xl, colA[j + 2]) + (XLL));                \
    half4 n2 = *(const half4*)(urow(xl, colA[j + 3]) + (XLL));                \
    AEDGE(p1, d, acc);                                                        \
    AEDGE(p2, dB, accB);                                                      \
    p1 = n1; p2 = n2;                                                         \
  }                                                                           \
  if (j < end)     AEDGE(p1, d, acc);                                         \
  if (j + 1 < end) AEDGE(p2, dB, accB);                                       \
  if (j + 2 < end) {                                                          \
    half4 n1 = *(const half4*)(urow(xl, colA[j + 2]) + (XLL));                \
    AEDGE(n1, d, acc);                                                        \
  }                                                                           \
  d += dB;                                                                    \
  acc.x += accB.x; acc.y += accB.y; acc.z += accB.z; acc.w += accB.w;

__global__ __launch_bounds__(256) void attn_concat_kernel(
    const _Float16* __restrict__ xl, const _Float16* __restrict__ xr,
    const float* __restrict__ att, const int* __restrict__ rowptr,
    const int* __restrict__ colA, _Float16* __restrict__ out,
    const int* __restrict__ batch, float* __restrict__ stats) {
  __shared__ float sv[4 * HC];
  int t = threadIdx.x;
  int node = blockIdx.x * 4 + (t >> 6);
  int lane = t & 63;
  if (lane < 44) {  // node < N always (grid = N/4 exactly)
    float4 avf = *(const float4*)(att + lane * 4);
    half2v ava, avb;
    ava[0] = (_Float16)avf.x; ava[1] = (_Float16)avf.y;
    avb[0] = (_Float16)avf.z; avb[1] = (_Float16)avf.w;
    const half2v lk2 = {(_Float16)0.2f, (_Float16)0.2f};
    size_t base = (size_t)node * HC + lane * 4;
    half4 xrv = *(const half4*)(xr + base);
    half2v xrl = xrv.lo, xrh = xrv.hi;
    half4 rv = *(const half4*)(out + base);  // residual+bias (hoisted read)
    ATTN_BODY(lane * 4)
    float rd = 1.0f / (d + 1e-16f);
    float4 o;
    o.x = fmaf(acc.x, rd, (float)rv[0]);
    o.y = fmaf(acc.y, rd, (float)rv[1]);
    o.z = fmaf(acc.z, rd, (float)rv[2]);
    o.w = fmaf(acc.w, rd, (float)rv[3]);
    half4 st;
    st[0] = (_Float16)o.x; st[1] = (_Float16)o.y;
    st[2] = (_Float16)o.z; st[3] = (_Float16)o.w;
    *(half4*)(out + base) = st;
    *(float4*)(&sv[(t >> 6) * HC + lane * 4]) = o;
  }
  __syncthreads();
  if (t < HC) {
    int b = blockIdx.x;
    int chunk = b & (NCHUNK - 1);
    int g0 = batch[b * 4];
    float s = 0.0f, ss = 0.0f;
    float sB = 0.0f, ssB = 0.0f;
    int gB = -1;
#pragma unroll
    for (int w = 0; w < 4; w++) {
      int g = batch[b * 4 + w];
      float v = sv[w * HC + t];
      if (g == g0) {
        s += v;
        ss = fmaf(v, v, ss);
      } else {  // rare graph-straddle
        gB = g; sB += v; ssB = fmaf(v, v, ssB);
      }
    }
    atomicAdd(&stats[(g0 * NCHUNK + chunk) * HC + t], s);
    atomicAdd(&stats[SQOFF + (g0 * NCHUNK + chunk) * HC + t], ss);
    if (gB >= 0) {
      atomicAdd(&stats[(gB * NCHUNK + chunk) * HC + t], sB);
      atomicAdd(&stats[SQOFF + (gB * NCHUNK + chunk) * HC + t], ssB);
    }
  }
}

__global__ __launch_bounds__(256) void attn_mean_kernel(
    const _Float16* __restrict__ xl, const _Float16* __restrict__ xr,
    const float* __restrict__ att, const int* __restrict__ rowptr,
    const int* __restrict__ colA, const float* __restrict__ res16,
    float* __restrict__ out16) {
  int t = threadIdx.x;
  int node = blockIdx.x * 4 + (t >> 6);
  int lane = t & 63;
  if (node >= N_NODES) return;
  int L = (lane < 44) ? lane : 0;  // lanes 44..63 ride along (zeroed later)
  float4 avf = *(const float4*)(att + L * 4);
  half2v ava, avb;
  ava[0] = (_Float16)avf.x; ava[1] = (_Float16)avf.y;
  avb[0] = (_Float16)avf.z; avb[1] = (_Float16)avf.w;
  const half2v lk2 = {(_Float16)0.2f, (_Float16)0.2f};
  size_t base = (size_t)node * HC + L * 4;
  half4 xrv = *(const half4*)(xr + base);
  half2v xrl = xrv.lo, xrh = xrv.hi;
  ATTN_BODY(L * 4)
  float rd = 1.0f / (d + 1e-16f);
  float4 o;
  o.x = (lane < 44) ? acc.x * rd : 0.0f;
  o.y = (lane < 44) ? acc.y * rd : 0.0f;
  o.z = (lane < 44) ? acc.z * rd : 0.0f;
  o.w = (lane < 44) ? acc.w * rd : 0.0f;
#pragma unroll
  for (int w = 4; w <= 32; w <<= 1) {
    o.x += __shfl_xor(o.x, w);
    o.y += __shfl_xor(o.y, w);
    o.z += __shfl_xor(o.z, w);
    o.w += __shfl_xor(o.w, w);
  }
  if (lane < 4) {
    const float* rp = res16 + (size_t)node * 16 + lane * 4;
    float4 r = *(const float4*)rp;
    float4 ov;
    ov.x = fmaxf(fmaf(o.x, 1.0f / 11.0f, r.x), 0.0f);
    ov.y = fmaxf(fmaf(o.y, 1.0f / 11.0f, r.y), 0.0f);
    ov.z = fmaxf(fmaf(o.z, 1.0f / 11.0f, r.z), 0.0f);
    ov.w = fmaxf(fmaf(o.w, 1.0f / 11.0f, r.w), 0.0f);
    *(float4*)(out16 + (size_t)node * 16 + lane * 4) = ov;
  }
}

// =====================================================================
// res16 = normApply(h) @ c5_Wres(176x16) + c5_b   (norm+relu fused in
// load; h is fp16 trunk)
// =====================================================================
__global__ __launch_bounds__(256) void res16_kernel(const _Float16* __restrict__ h,
                                                    const float* __restrict__ scsh,
                                                    const int* __restrict__ batch,
                                                    const float* __restrict__ Wres,
                                                    const float* __restrict__ b16,
                                                    float* __restrict__ res16) {
  __shared__ float Ws[176 * 16];
  __shared__ float hs[16 * 176];
  int t = threadIdx.x;
  for (int i = t; i < 176 * 16; i += 256) Ws[i] = Wres[i];
  int n0 = blockIdx.x * 16;
  for (int i = t; i < 16 * 176; i += 256) {
    int row = i / 176, k = i - row * 176;
    int g = batch[n0 + row];
    float v = (float)h[(size_t)n0 * HC + i];
    hs[i] = fmaxf(fmaf(v, scsh[g * HC + k], scsh[(NGRAPH + g) * HC + k]), 0.0f);
  }
  __syncthreads();
  int tx = t & 15, ty = t >> 4;
  float acc = b16[tx];
  for (int k = 0; k < HC; k++) acc = fmaf(hs[ty * HC + k], Ws[k * 16 + tx], acc);
  res16[(size_t)(n0 + ty) * 16 + tx] = acc;
}

// =====================================================================
// Head MLP
// =====================================================================
__global__ __launch_bounds__(256) void head_kernel(
    const float* __restrict__ in16, const float* __restrict__ Wo1,
    const float* __restrict__ bo1, const float* __restrict__ Wo2,
    const float* __restrict__ bo2, const float* __restrict__ Wc,
    const float* __restrict__ bc, float* __restrict__ outp) {
  __shared__ float w1[256], w2[512], wcS[320], b1[16], b2[32], bcS[10];
  int t = threadIdx.x;
  for (int i = t; i < 256; i += 256) w1[i] = Wo1[i];
  for (int i = t; i < 512; i += 256) w2[i] = Wo2[i];
  for (int i = t; i < 320; i += 256) wcS[i] = Wc[i];
  if (t < 16) b1[t] = bo1[t];
  if (t < 32) b2[t] = bo2[t];
  if (t < 10) bcS[t] = bc[t];
  __syncthreads();
  int n = blockIdx.x * 256 + t;
  if (n >= N_NODES) return;
  float x[16];
#pragma unroll
  for (int i = 0; i < 16; i++) x[i] = in16[(size_t)n * 16 + i];
  float o1[16];
#pragma unroll
  for (int j = 0; j < 16; j++) {
    float a = b1[j];
#pragma unroll
    for (int k = 0; k < 16; k++) a = fmaf(x[k], w1[k * 16 + j], a);
    o1[j] = fmaxf(a, 0.0f);
  }
  float o2[32];
#pragma unroll
  for (int j = 0; j < 32; j++) {
    float a = b2[j];
#pragma unroll
    for (int k = 0; k < 16; k++) a = fmaf(o1[k], w2[k * 32 + j], a);
    o2[j] = fmaxf(a, 0.0f);
  }
#pragma unroll
  for (int j = 0; j < 10; j++) {
    float a = bcS[j];
#pragma unroll
    for (int k = 0; k < 32; k++) a = fmaf(o2[k], wcS[k * 10 + j], a);
    outp[(size_t)n * 10 + j] = a;
  }
}

// =====================================================================
extern "C" void kernel_launch(void* const* d_in, const int* in_sizes, int n_in,
                              void* d_out, int out_size, void* d_ws, size_t ws_size,
                              hipStream_t stream) {
  (void)in_sizes; (void)n_in; (void)out_size; (void)ws_size;
  const float* x     = (const float*)d_in[0];
  const int*   ei    = (const int*)d_in[1];
  const int*   srcE  = ei;
  const int*   dstE  = ei + N_EDGES;
  const int*   batch = (const int*)d_in[2];
  const float* W_pre = (const float*)d_in[3];
  const float* b_pre = (const float*)d_in[4];
  const float* gn_w  = (const float*)d_in[5];
  const float* gn_b  = (const float*)d_in[6];
  const float* gn_ms = (const float*)d_in[7];
  const float* cWl   = (const float*)d_in[8];
  const float* cWr   = (const float*)d_in[9];
  const float* cAtt  = (const float*)d_in[10];
  const float* cB    = (const float*)d_in[11];
  const float* cWres = (const float*)d_in[12];
  const float* c5Wl  = (const float*)d_in[13];
  const float* c5Wr  = (const float*)d_in[14];
  const float* c5Att = (const float*)d_in[15];
  const float* c5b   = (const float*)d_in[16];
  const float* c5Wres= (const float*)d_in[17];
  const float* Wo1   = (const float*)d_in[18];
  const float* bo1   = (const float*)d_in[19];
  const float* Wo2   = (const float*)d_in[20];
  const float* bo2   = (const float*)d_in[21];
  const float* Wc    = (const float*)d_in[22];
  const float* bc    = (const float*)d_in[23];

  const size_t FB = (size_t)N_NODES * HC;
  const size_t STB2 = (size_t)2 * NGRAPH * NCHUNK * HC;  // chunked stats buffer
  float* ws    = (float*)d_ws;
  float* buf0  = ws;           // trunk h: fp16 storage in fp32-sized slot
  float* buf1  = ws + FB;      // xl: fp16 storage
  float* buf2  = ws + 2 * FB;  // xr: fp16 storage
  float* buf3  = ws + 3 * FB;  // trunk o: fp16 storage
  float* res16 = ws + 4 * FB;
  float* out16 = res16 + (size_t)N_NODES * 16;
  float* stats2 = out16 + (size_t)N_NODES * 16;        // 5 chunked buffers (zeroed)
  int* deg     = (int*)(stats2 + 5 * STB2);            // zeroed with stats
  int* fill    = deg + N_NODES;                        // zeroed with stats
  float* scsh  = (float*)(fill + N_NODES);
  _Float16* wph = (_Float16*)(scsh + (size_t)2 * NGRAPH * HC);  // 991232 halves
  int* ibase   = (int*)((char*)wph + (size_t)991232 * 2);
  int* cntInt  = ibase;
  int* gstart  = ibase + 64;                           // 65 ints
  int* rowptr  = gstart + 65;
  int* colA    = rowptr + N_NODES + 1;
  int* bsum    = colA + N_EDGES;

  const int NB = (N_NODES + 255) / 256;

  // single memset: 5 chunked stats buffers + deg + fill (contiguous)
  hipMemsetAsync(stats2, 0, sizeof(float) * 5 * STB2 + sizeof(int) * 2 * N_NODES, stream);

  prep_kernel<<<(TOT_PAIRS + 255) / 256, 256, 0, stream>>>(W_pre, cWl, cWr, cWres, c5Wl, c5Wr, wph);
  cnt_bsearch_kernel<<<1, 64, 0, stream>>>(batch, cntInt, gstart);
  deg_hist_kernel<<<(N_EDGES + 255) / 256, 256, 0, stream>>>(dstE, deg);
  scan1_kernel<<<NB, 256, 0, stream>>>(deg, bsum);
  scan2_kernel<<<1, 256, 0, stream>>>(bsum, NB);
  scan3_kernel<<<NB, 256, 0, stream>>>(deg, bsum, rowptr);
  scatter_kernel<<<(N_EDGES + 255) / 256, 256, 0, stream>>>(srcE, dstE, rowptr, fill, colA);

  // pre: buf0 = fp16(x @ W_pre + b_pre), with fused layer-0 GraphNorm
  // partials via chunked atomics (fp32 accumulators pre-rounding)
  gemm_mfma_t<2, true, false><<<GX8 * 1 * 8, 256, 0, stream>>>(
      x, N_NODES, IN_F, 4, 1, wph, 0, nullptr, batch,
      b_pre, nullptr, nullptr, buf0, nullptr, nullptr,
      stats2, 1);
  gn_finalize_kernel<<<(NGRAPH * HC + 255) / 256, 256, 0, stream>>>(stats2, cntInt, gn_w, gn_b, gn_ms, 0, scsh);

  float* h = buf0;  // raw fp16 trunk; norm applied on the fly by consumers
  float* o = buf3;
  for (int i = 0; i < 4; i++) {
    const _Float16* Wcat_i = wph + PREH + (size_t)(3 * i) * MATH;
    gemm_mfma_t<3, false, true><<<GX8 * 3 * 8, 256, 0, stream>>>(
        h, N_NODES, HC, 6, 3, Wcat_i, MATH, scsh, batch,
        nullptr, nullptr, cB + i * HC, buf1, buf2, o,
        nullptr, 7);
    float* st = stats2 + (size_t)(i + 1) * STB2;
    attn_concat_kernel<<<NBLK_ATTN, 256, 0, stream>>>((const _Float16*)buf1, (const _Float16*)buf2,
                                                      cAtt + i * HC,
                                                      rowptr, colA, (_Float16*)o, batch, st);
    gn_finalize_kernel<<<(NGRAPH * HC + 255) / 256, 256, 0, stream>>>(st, cntInt, gn_w, gn_b, gn_ms, i + 1, scsh);
    float* tmp = h; h = o; o = tmp;
  }

  // conv5 (input = raw fp16 h with scsh row 4 fused in consumers)
  const _Float16* Wc5 = wph + PREH + (size_t)12 * MATH;
  gemm_mfma_t<3, false, true><<<GX8 * 2 * 8, 256, 0, stream>>>(
      h, N_NODES, HC, 6, 2, Wc5, MATH, scsh, batch,
      nullptr, nullptr, nullptr, buf1, buf2, nullptr,
      nullptr, 3);
  res16_kernel<<<N_NODES / 16, 256, 0, stream>>>((const _Float16*)h, scsh, batch, c5Wres, c5b, res16);
  attn_mean_kernel<<<(N_NODES + 3) / 4, 256, 0, stream>>>((const _Float16*)buf1, (const _Float16*)buf2,
                                                          c5Att, rowptr, colA, res16, out16);

  head_kernel<<<NB, 256, 0, stream>>>(out16, Wo1, bo1, Wo2, bo2, Wc, bc, (float*)d_out);
}